// Round 6
// baseline (632.933 us; speedup 1.0000x reference)
//
#include <hip/hip_runtime.h>
#include <hip/hip_bf16.h>
#include <math.h>

#define NQ_    65536
#define NV_    1558
#define HALF_V 779
#define VSPLIT 8
#define VCHUNK 195   // ceil(1558/8); ranges ascending in p

// ws layout in floats (total 4,452,352 floats = 17.8 MB)
#define WS_GFC   512        //   768
#define WS_GTH   1280       // 14080
#define WS_VF    15360      // 50176 (1558*32)
#define WS_C3A   65536      // 86016  (reused: bf16 weights after c3 conv2)
#define WS_C3B   151552     // 172032 (tail reused for c4 stat partials)
#define WS_C4A   323584     // 1376256 (head reused for c3 stat partials)
#define WS_C4B   1699840    // 2752512 (reused after apool(c4): idx/bestd/besti/vert4)

typedef __attribute__((ext_vector_type(8))) short bf16x8;
typedef __attribute__((ext_vector_type(4))) float f32x4;
typedef float float4a __attribute__((ext_vector_type(4), aligned(4)));  // 4B-aligned float4 load

__device__ __forceinline__ short f2b(float x) {
    union { __hip_bfloat16 h; short s; } u; u.h = __float2bfloat16(x); return u.s;
}

// ---------------- bilinear feature sampling (vertices) ----------------
__device__ __forceinline__ void bsample(const float* __restrict__ f, int C, int H, int W,
                                        float xn, float yn, float* __restrict__ o) {
    float x = (xn + 1.f) * 0.5f * (float)(W - 1);
    float y = (yn + 1.f) * 0.5f * (float)(H - 1);
    float x0f = floorf(x), y0f = floorf(y);
    float wx = x - x0f, wy = y - y0f;
    int x0 = (int)fminf(fmaxf(x0f, 0.f), (float)(W - 1));
    int x1 = (int)fminf(fmaxf(x0f + 1.f, 0.f), (float)(W - 1));
    int y0 = (int)fminf(fmaxf(y0f, 0.f), (float)(H - 1));
    int y1 = (int)fminf(fmaxf(y0f + 1.f, 0.f), (float)(H - 1));
    for (int c = 0; c < C; ++c) {
        const float* b = f + c * H * W;
        float v00 = b[y0 * W + x0], v01 = b[y0 * W + x1];
        float v10 = b[y1 * W + x0], v11 = b[y1 * W + x1];
        o[c] = v00 * (1.f - wx) * (1.f - wy) + v01 * wx * (1.f - wy)
             + v10 * (1.f - wx) * wy       + v11 * wx * wy;
    }
}

__global__ void feat_sample_k(const float* __restrict__ vert_xy,
                              const float* __restrict__ img,
                              const float* __restrict__ ft1,
                              float* __restrict__ vf) {
    int v = blockIdx.x * 64 + threadIdx.x;
    if (v >= NV_) return;
    float xn = vert_xy[v * 2 + 0], yn = vert_xy[v * 2 + 1];
    float tmp[8];
    bsample(img, 3, 256, 256, xn, yn, tmp);
    float* o = vf + v * 32;
    o[0] = tmp[0]; o[1] = tmp[1]; o[2] = tmp[2];
    bsample(ft1, 8, 64, 64, xn, yn, tmp);
    #pragma unroll
    for (int c = 0; c < 8; ++c) o[3 + c] = tmp[c];
}

// ---------------- conv2d 3x3 pad1: 2 pixels x CB channels per thread,
// ---------------- fused per-(channel,block) sum/sumsq partials ----------------
template <int CB>
__global__ __launch_bounds__(256) void conv2_k(
    const float* __restrict__ in, const float* __restrict__ w,
    float* __restrict__ out, float* __restrict__ part,
    int Cin, int H, int W) {
    int c0 = blockIdx.y * CB;
    int tid = threadIdx.x;
    int px0 = (blockIdx.x * 256 + tid) * 2;
    int HW = H * W;
    int y = px0 / W, x = px0 % W;      // x is even
    bool interior = (x > 0) && (x + 3 < W);
    float acc0[CB], acc1[CB];
    #pragma unroll
    for (int j = 0; j < CB; ++j) { acc0[j] = 0.f; acc1[j] = 0.f; }
    const float* wbase = w + c0 * Cin * 9;
    #pragma unroll 2
    for (int ci = 0; ci < Cin; ++ci) {
        const float* ip = in + ci * HW;
        float win[3][5];
        #pragma unroll
        for (int r = 0; r < 3; ++r) {
            int yy = y + r - 1;
            bool okY = (yy >= 0) && (yy < H);
            const float* rp = ip + yy * W;
            if (okY && interior) {
                // single 4B-aligned 16B load covers rp[x-1..x+2]
                float4a m4 = *(const float4a*)(rp + x - 1);
                win[r][0] = m4.x; win[r][1] = m4.y; win[r][2] = m4.z; win[r][3] = m4.w;
                win[r][4] = rp[x + 3];
            } else if (okY) {
                win[r][0] = (x > 0) ? rp[x - 1] : 0.f;
                win[r][1] = rp[x]; win[r][2] = rp[x + 1];
                win[r][3] = (x + 2 < W) ? rp[x + 2] : 0.f;
                win[r][4] = (x + 3 < W) ? rp[x + 3] : 0.f;
            } else {
                win[r][0] = win[r][1] = win[r][2] = win[r][3] = win[r][4] = 0.f;
            }
        }
        const float* wc = wbase + ci * 9;
        #pragma unroll
        for (int j = 0; j < CB; ++j) {
            const float* wj = wc + j * Cin * 9;
            #pragma unroll
            for (int r = 0; r < 3; ++r) {
                float w0 = wj[r * 3 + 0], w1 = wj[r * 3 + 1], w2 = wj[r * 3 + 2];
                acc0[j] = fmaf(w0, win[r][0], fmaf(w1, win[r][1], fmaf(w2, win[r][2], acc0[j])));
                acc1[j] = fmaf(w0, win[r][1], fmaf(w1, win[r][2], fmaf(w2, win[r][3], acc1[j])));
            }
        }
    }
    #pragma unroll
    for (int j = 0; j < CB; ++j)
        *(float2*)(out + (c0 + j) * HW + px0) = make_float2(acc0[j], acc1[j]);

    // fused stats: per-(channel, block) sum / sumsq
    __shared__ float sred[4][CB][2];
    int lane = tid & 63, wave = tid >> 6;
    #pragma unroll
    for (int j = 0; j < CB; ++j) {
        float s = acc0[j] + acc1[j];
        float qq = acc0[j] * acc0[j] + acc1[j] * acc1[j];
        #pragma unroll
        for (int off = 1; off < 64; off <<= 1) {
            s  += __shfl_xor(s, off, 64);
            qq += __shfl_xor(qq, off, 64);
        }
        if (lane == 0) { sred[wave][j][0] = s; sred[wave][j][1] = qq; }
    }
    __syncthreads();
    if (tid < CB) {
        float s = sred[0][tid][0] + sred[1][tid][0] + sred[2][tid][0] + sred[3][tid][0];
        float qq = sred[0][tid][1] + sred[1][tid][1] + sred[2][tid][1] + sred[3][tid][1];
        int c = c0 + tid;
        part[(c * gridDim.x + blockIdx.x) * 2 + 0] = s;
        part[(c * gridDim.x + blockIdx.x) * 2 + 1] = qq;
    }
}

// ---------------- LN apply (+relu); per-block recompute of (m, inv) from partials ----------------
__global__ __launch_bounds__(256) void ln_apply_k(
    float* __restrict__ buf, const float* __restrict__ part,
    const float* __restrict__ g, const float* __restrict__ b,
    int HW, int nb, float invHW) {
    int i = blockIdx.x * 256 + threadIdx.x;
    int c = i / HW;      // HW is a power of two; uniform per block
    int hw = i % HW;
    float s = 0.f, s2 = 0.f;
    for (int j = 0; j < nb; ++j) {           // wave-uniform scalar loads
        s  += part[(c * nb + j) * 2 + 0];
        s2 += part[(c * nb + j) * 2 + 1];
    }
    float m = s * invHW;
    float var = s2 * invHW - m * m;
    if (var < 0.f) var = 0.f;
    float inv = rsqrtf(var + 1e-6f);
    float x = buf[i];
    float r = fmaf((x - m) * inv, g[hw], b[hw]);
    buf[i] = fmaxf(r, 0.f);
}

// ---------------- adaptive 3x3 avg pool -> gf_cat[c][colOff + bin] ----------------
__global__ __launch_bounds__(256) void apool3_k(const float* __restrict__ in,
                                                float* __restrict__ gfc,
                                                int H, int W, int colOff) {
    int c = (int)blockIdx.x / 9;
    int bin = (int)blockIdx.x % 9;
    int bh = bin / 3, bw = bin % 3;
    int hs = bh * H / 3, he = ((bh + 1) * H + 2) / 3;
    int wsx = bw * W / 3, we = ((bw + 1) * W + 2) / 3;
    int rw = we - wsx, rh = he - hs, n = rw * rh;
    const float* b = in + c * H * W;
    float s = 0.f;
    for (int t = threadIdx.x; t < n; t += 256) {
        int iy = t / rw, ix = t % rw;
        s += b[(hs + iy) * W + (wsx + ix)];
    }
    __shared__ float rs[256];
    rs[threadIdx.x] = s;
    __syncthreads();
    for (int st = 128; st > 0; st >>= 1) {
        if (threadIdx.x < st) rs[threadIdx.x] += rs[threadIdx.x + st];
        __syncthreads();
    }
    if (threadIdx.x == 0) gfc[c * 18 + colOff + bin] = rs[0] / (float)n;
}

// ---------------- conv1d (42->779) + LN(18) + relu ----------------
__global__ __launch_bounds__(64) void gt1_k(const float* __restrict__ gfc,
                                            const float* __restrict__ w,
                                            const float* __restrict__ g,
                                            const float* __restrict__ b,
                                            float* __restrict__ outh) {
    int o = blockIdx.x;     // 779
    int p = threadIdx.x;
    __shared__ float vals[18];
    if (p < 18) {
        float acc = 0.f;
        const float* wo = w + o * 42 * 3;
        for (int c = 0; c < 42; ++c) {
            const float* gr = gfc + c * 18;
            #pragma unroll
            for (int k = 0; k < 3; ++k) {
                int pk = p + k - 1;
                if (pk >= 0 && pk < 18) acc = fmaf(wo[c * 3 + k], gr[pk], acc);
            }
        }
        vals[p] = acc;
    }
    __syncthreads();
    if (p < 18) {
        float s = 0.f, s2 = 0.f;
        #pragma unroll
        for (int j = 0; j < 18; ++j) { float x = vals[j]; s += x; s2 += x * x; }
        float m = s / 18.f;
        float var = s2 / 18.f - m * m;
        if (var < 0.f) var = 0.f;
        float inv = rsqrtf(var + 1e-6f);
        float r = fmaf((vals[p] - m) * inv, g[p], b[p]);
        outh[o * 18 + p] = fmaxf(r, 0.f);
    }
}

// ---------------- conv1d (779->1558) + LN(18) + relu -> vf cols 11..28 ----------------
// 4 waves per block; each wave covers a contiguous quarter of the 779 channels.
__global__ __launch_bounds__(256) void gt2_k(const float* __restrict__ h,
                                             const float* __restrict__ w,
                                             const float* __restrict__ g,
                                             const float* __restrict__ b,
                                             float* __restrict__ vf) {
    int o = blockIdx.x;     // 1558
    int t = threadIdx.x, lane = t & 63, wave = t >> 6;
    __shared__ float red[4][18];
    float part[18];
    #pragma unroll
    for (int p = 0; p < 18; ++p) part[p] = 0.f;
    int c0 = wave * 195;
    int c1 = c0 + 195; if (c1 > HALF_V) c1 = HALF_V;
    for (int c = c0 + lane; c < c1; c += 64) {
        const float* wr = w + (o * HALF_V + c) * 3;
        float w0 = wr[0], w1 = wr[1], w2 = wr[2];
        const float* hr = h + c * 18;
        float hv[18];
        #pragma unroll
        for (int p = 0; p < 18; ++p) hv[p] = hr[p];
        #pragma unroll
        for (int p = 0; p < 18; ++p) {
            float a = w1 * hv[p];
            if (p > 0)  a = fmaf(w0, hv[p - 1], a);
            if (p < 17) a = fmaf(w2, hv[p + 1], a);
            part[p] += a;
        }
    }
    #pragma unroll
    for (int p = 0; p < 18; ++p) {
        float vv = part[p];
        #pragma unroll
        for (int off = 32; off > 0; off >>= 1) vv += __shfl_xor(vv, off, 64);
        part[p] = vv;
    }
    if (lane == 0) {
        #pragma unroll
        for (int p = 0; p < 18; ++p) red[wave][p] = part[p];
    }
    __syncthreads();
    if (t < 18) {
        float s = red[0][t] + red[1][t] + red[2][t] + red[3][t];
        red[0][t] = s;
    }
    __syncthreads();
    if (t < 18) {
        float s = 0.f, s2 = 0.f;
        #pragma unroll
        for (int j = 0; j < 18; ++j) { float x = red[0][j]; s += x; s2 += x * x; }
        float m = s / 18.f;
        float var = s2 / 18.f - m * m;
        if (var < 0.f) var = 0.f;
        float inv = rsqrtf(var + 1e-6f);
        float r = fmaf((red[0][t] - m) * inv, g[t], b[t]);
        vf[o * 32 + 11 + t] = fmaxf(r, 0.f);
    }
}

// ---------------- argmin: one THREAD per query, wave-uniform vertex scan ----------------
__global__ void vprep_k(const float* __restrict__ vert, float4* __restrict__ v4) {
    int i = blockIdx.x * 64 + threadIdx.x;
    if (i >= NV_) return;
    float x = vert[i * 3 + 0], y = vert[i * 3 + 1], z = vert[i * 3 + 2];
    float pn = __fadd_rn(__fadd_rn(__fmul_rn(x, x), __fmul_rn(y, y)), __fmul_rn(z, z));
    v4[i] = make_float4(x, y, z, pn);
}

__global__ __launch_bounds__(256) void argmin_part_k(
    const float* __restrict__ v, const float4* __restrict__ v4,
    float* __restrict__ bestd, int* __restrict__ besti) {
    int q = blockIdx.x * 256 + threadIdx.x;
    int r = blockIdx.y;
    int p0 = r * VCHUNK;
    int p1 = p0 + VCHUNK; if (p1 > NV_) p1 = NV_;
    float vx = v[q * 3 + 0], vy = v[q * 3 + 1], vz = v[q * 3 + 2];
    float vn = __fadd_rn(__fadd_rn(__fmul_rn(vx, vx), __fmul_rn(vy, vy)), __fmul_rn(vz, vz));
    float best = 3.4e38f;
    int bi = p0;
    // d2 = (|v|^2 + |p|^2) - 2*(v.p); np rounding preserved (no fma contraction).
    // v4[p] is wave-uniform -> scalar K$ loads; strict < keeps smallest p on ties.
    #pragma unroll 4
    for (int p = p0; p < p1; ++p) {
        float4 pv = v4[p];
        float dot = __fadd_rn(__fadd_rn(__fmul_rn(vx, pv.x), __fmul_rn(vy, pv.y)), __fmul_rn(vz, pv.z));
        float d2 = __fsub_rn(__fadd_rn(vn, pv.w), __fmul_rn(2.f, dot));
        if (d2 < best) { best = d2; bi = p; }
    }
    bestd[r * NQ_ + q] = best;
    besti[r * NQ_ + q] = bi;
}

__global__ __launch_bounds__(256) void argmin_comb_k(
    const float* __restrict__ bestd, const int* __restrict__ besti,
    int* __restrict__ idx) {
    int q = blockIdx.x * 256 + threadIdx.x;
    float best = bestd[q];
    int bi = besti[q];
    #pragma unroll
    for (int r = 1; r < VSPLIT; ++r) {
        float d = bestd[r * NQ_ + q];
        int i2 = besti[r * NQ_ + q];
        if (d < best) { best = d; bi = i2; }   // ranges ascend in p; strict < keeps first min
    }
    idx[q] = bi;
}

// ---------------- weight f32 -> bf16 (with row zero-padding) ----------------
// wb layout (shorts): [0,9216) atw1 ; [9216,10752) atw2 pad to 16 rows ;
//                     [10752,19968) fcw1 ; [19968,24576) fcw2 pad to 48 rows
__global__ void wcvt_k(const float* __restrict__ atw1, const float* __restrict__ atw2,
                       const float* __restrict__ fcw1, const float* __restrict__ fcw2,
                       short* __restrict__ wb) {
    int i = blockIdx.x * 256 + threadIdx.x;   // grid 96 -> 24576
    short v = 0;
    if (i < 9216) v = f2b(atw1[i]);
    else if (i < 10752) { int j = i - 9216; v = (j < 576) ? f2b(atw2[j]) : (short)0; }
    else if (i < 19968) v = f2b(fcw1[i - 10752]);
    else { int j = i - 19968; v = (j < 3840) ? f2b(fcw2[j]) : (short)0; }
    wb[i] = v;
}

// ---------------- MFMA MLP: 16 queries per wave, 64 per block ----------------
#define YP 104   // padded LDS row stride in shorts (2-way bank aliasing only)

__global__ __launch_bounds__(256) void mlp_mfma_k(
    const int* __restrict__ idx,
    const float* __restrict__ vvis, const float* __restrict__ qvis,
    const float* __restrict__ ixy, const float* __restrict__ fxy,
    const float* __restrict__ lat, const float* __restrict__ vf,
    const short* __restrict__ wb, float* __restrict__ out) {
    __shared__ short Y[64 * YP];
    __shared__ short Hb[64 * YP];
    __shared__ float A6[64 * 8];
    int t = threadIdx.x;
    int lane = t & 63, wave = t >> 6;
    int q0 = blockIdx.x * 64;

    // ---- y build: 4 lanes per query, bf16 into LDS; keep f32 copy in regs ----
    int ql = t >> 2, part = t & 3;
    int q = q0 + ql;
    int bi = idx[q];
    int bi2 = bi + HALF_V; if (bi2 >= NV_) bi2 -= NV_;
    const float* f  = vf + bi * 32;
    const float* ft = vf + bi2 * 32;
    float vis = vvis[bi], vist = vvis[bi2];
    short* yr = &Y[ql * YP];
    float myv[24];
    #pragma unroll
    for (int jj = 0; jj < 24; ++jj) {
        int j = part * 24 + jj;
        float val;
        if (j < 3)       val = ixy[q * 3 + j];
        else if (j < 11) val = fxy[q * 8 + j - 3];
        else if (j < 22) val = f[j - 11] * vis;
        else if (j < 33) val = ft[j - 22] * vist;
        else if (j < 51) val = f[11 + j - 33] * vis;
        else if (j < 69) val = ft[11 + j - 51] * vist;
        else if (j < 93) val = lat[q * 24 + j - 69];
        else if (j == 93) val = qvis[q];
        else if (j == 94) val = vis;
        else              val = vist;
        myv[jj] = val;
        yr[j] = f2b(val);
    }
    __syncthreads();

    int nloc = lane & 15, quad = lane >> 4;
    const short* Ya = &Y[(wave * 16 + nloc) * YP];
    const short* Ha = &Hb[(wave * 16 + nloc) * YP];
    int hrow = wave * 16 + quad * 4;    // C-layout row base for this lane

    // ---- GEMM1: H = relu(Y x atw1^T) ----
    f32x4 acc[6];
    #pragma unroll
    for (int nt = 0; nt < 6; ++nt) acc[nt] = (f32x4){0.f, 0.f, 0.f, 0.f};
    #pragma unroll
    for (int k0 = 0; k0 < 96; k0 += 32) {
        bf16x8 a = *(const bf16x8*)(Ya + k0 + quad * 8);
        #pragma unroll
        for (int nt = 0; nt < 6; ++nt) {
            bf16x8 b = *(const bf16x8*)(wb + (nt * 16 + nloc) * 96 + k0 + quad * 8);
            acc[nt] = __builtin_amdgcn_mfma_f32_16x16x32_bf16(a, b, acc[nt], 0, 0, 0);
        }
    }
    #pragma unroll
    for (int nt = 0; nt < 6; ++nt)
        #pragma unroll
        for (int r = 0; r < 4; ++r)
            Hb[(hrow + r) * YP + nt * 16 + nloc] = f2b(fmaxf(acc[nt][r], 0.f));
    __syncthreads();

    // ---- GEMM2: at6 = sigmoid(H x atw2^T) ----
    {
        const short* w2 = wb + 9216;
        f32x4 a2 = (f32x4){0.f, 0.f, 0.f, 0.f};
        #pragma unroll
        for (int k0 = 0; k0 < 96; k0 += 32) {
            bf16x8 a = *(const bf16x8*)(Ha + k0 + quad * 8);
            bf16x8 b = *(const bf16x8*)(w2 + nloc * 96 + k0 + quad * 8);
            a2 = __builtin_amdgcn_mfma_f32_16x16x32_bf16(a, b, a2, 0, 0, 0);
        }
        if (nloc < 6) {
            #pragma unroll
            for (int r = 0; r < 4; ++r)
                A6[(hrow + r) * 8 + nloc] = 1.f / (1.f + expf(-a2[r]));
        }
    }
    __syncthreads();

    // ---- scale Y in place from f32 register copy ----
    {
        const float* ap = &A6[ql * 8];
        #pragma unroll
        for (int jj = 0; jj < 24; ++jj) {
            int j = part * 24 + jj;
            float s;
            if (j < 11)      s = ap[0];
            else if (j < 22) s = ap[1];
            else if (j < 33) s = ap[2];
            else if (j < 51) s = ap[3];
            else if (j < 69) s = ap[4];
            else if (j < 93) s = ap[5];
            else             s = 1.f;
            yr[j] = f2b(myv[jj] * s);
        }
    }
    __syncthreads();

    // ---- GEMM3: H2 = relu(Y2 x fcw1^T) ----
    {
        const short* w3 = wb + 10752;
        #pragma unroll
        for (int nt = 0; nt < 6; ++nt) acc[nt] = (f32x4){0.f, 0.f, 0.f, 0.f};
        #pragma unroll
        for (int k0 = 0; k0 < 96; k0 += 32) {
            bf16x8 a = *(const bf16x8*)(Ya + k0 + quad * 8);
            #pragma unroll
            for (int nt = 0; nt < 6; ++nt) {
                bf16x8 b = *(const bf16x8*)(w3 + (nt * 16 + nloc) * 96 + k0 + quad * 8);
                acc[nt] = __builtin_amdgcn_mfma_f32_16x16x32_bf16(a, b, acc[nt], 0, 0, 0);
            }
        }
        #pragma unroll
        for (int nt = 0; nt < 6; ++nt)
            #pragma unroll
            for (int r = 0; r < 4; ++r)
                Hb[(hrow + r) * YP + nt * 16 + nloc] = f2b(fmaxf(acc[nt][r], 0.f));
    }
    __syncthreads();

    // ---- GEMM4: OUT = H2 x fcw2^T ----
    {
        const short* w4 = wb + 19968;
        f32x4 oacc[3];
        #pragma unroll
        for (int nt = 0; nt < 3; ++nt) oacc[nt] = (f32x4){0.f, 0.f, 0.f, 0.f};
        #pragma unroll
        for (int k0 = 0; k0 < 96; k0 += 32) {
            bf16x8 a = *(const bf16x8*)(Ha + k0 + quad * 8);
            #pragma unroll
            for (int nt = 0; nt < 3; ++nt) {
                bf16x8 b = *(const bf16x8*)(w4 + (nt * 16 + nloc) * 96 + k0 + quad * 8);
                oacc[nt] = __builtin_amdgcn_mfma_f32_16x16x32_bf16(a, b, oacc[nt], 0, 0, 0);
            }
        }
        #pragma unroll
        for (int nt = 0; nt < 3; ++nt) {
            int oc = nt * 16 + nloc;
            if (oc < 40) {
                #pragma unroll
                for (int r = 0; r < 4; ++r)
                    out[(q0 + hrow + r) * 40 + oc] = oacc[nt][r];
            }
        }
    }
}

extern "C" void kernel_launch(void* const* d_in, const int* in_sizes, int n_in,
                              void* d_out, int out_size, void* d_ws, size_t ws_size,
                              hipStream_t stream) {
    const float* vert_xy = (const float*)d_in[0];
    const float* ft1     = (const float*)d_in[1];
    const float* ft_xy   = (const float*)d_in[2];
    const float* vert    = (const float*)d_in[3];
    const float* v       = (const float*)d_in[4];
    const float* vvis    = (const float*)d_in[5];
    const float* qvis    = (const float*)d_in[6];
    const float* ixy     = (const float*)d_in[7];
    const float* img     = (const float*)d_in[8];
    const float* lat     = (const float*)d_in[9];
    const float* fcw1    = (const float*)d_in[10];
    const float* fcw2    = (const float*)d_in[11];
    const float* atw1    = (const float*)d_in[12];
    const float* atw2    = (const float*)d_in[13];
    const float* gtw1    = (const float*)d_in[14];
    const float* gtg1    = (const float*)d_in[15];
    const float* gtb1    = (const float*)d_in[16];
    const float* gtw2    = (const float*)d_in[17];
    const float* gtg2    = (const float*)d_in[18];
    const float* gtb2    = (const float*)d_in[19];
    const float* c3w1    = (const float*)d_in[20];
    const float* c3g1    = (const float*)d_in[21];
    const float* c3b1    = (const float*)d_in[22];
    const float* c3w2    = (const float*)d_in[23];
    const float* c3g2    = (const float*)d_in[24];
    const float* c3b2    = (const float*)d_in[25];
    const float* c4w1    = (const float*)d_in[26];
    const float* c4g1    = (const float*)d_in[27];
    const float* c4b1    = (const float*)d_in[28];
    const float* c4w2    = (const float*)d_in[29];
    const float* c4g2    = (const float*)d_in[30];
    const float* c4b2    = (const float*)d_in[31];
    float* out = (float*)d_out;
    float* ws  = (float*)d_ws;
    float* gfc   = ws + WS_GFC;
    float* gth   = ws + WS_GTH;
    float* vfb   = ws + WS_VF;
    float* c3a   = ws + WS_C3A;
    float* c3bb  = ws + WS_C3B;
    float* c4a   = ws + WS_C4A;
    float* c4bb  = ws + WS_C4B;
    float* part_c3 = ws + WS_C4A;            // c4a not live during c3 chain
    short* wbf     = (short*)(ws + WS_C3A);  // c3a dead after c3 conv2 (24576 shorts)
    float* part_c4 = ws + WS_C3B;            // c3bb dead after apool(c3)
    // after apool(c4), c4bb region is dead; carve argmin scratch out of it:
    int*    idx   = (int*)(ws + WS_C4B);                     // 65536 ints
    float*  bestd = ws + WS_C4B + 65536;                     // 8*65536 floats
    int*    besti = (int*)(ws + WS_C4B + 65536 + 524288);    // 8*65536 ints
    float4* vert4 = (float4*)(ws + WS_C4B + 65536 + 1048576); // 1558 float4

    feat_sample_k<<<25, 64, 0, stream>>>(vert_xy, img, ft1, vfb);

    // c3 chain: ft1 (8,64,64) -> (21) -> (42) -> pool -> gfc cols 9..17
    conv2_k<7><<<dim3(8, 3), 256, 0, stream>>>(ft1, c3w1, c3a, part_c3, 8, 64, 64);
    ln_apply_k<<<21 * 16, 256, 0, stream>>>(c3a, part_c3, c3g1, c3b1, 4096, 8, 1.f / 4096.f);
    conv2_k<7><<<dim3(8, 6), 256, 0, stream>>>(c3a, c3w2, c3bb, part_c3, 21, 64, 64);
    wcvt_k<<<96, 256, 0, stream>>>(atw1, atw2, fcw1, fcw2, wbf);  // c3a now dead
    ln_apply_k<<<42 * 16, 256, 0, stream>>>(c3bb, part_c3, c3g2, c3b2, 4096, 8, 1.f / 4096.f);
    apool3_k<<<42 * 9, 256, 0, stream>>>(c3bb, gfc, 64, 64, 9);

    // c4 chain: img (3,256,256) -> (21) -> (42) -> pool -> gfc cols 0..8
    conv2_k<7><<<dim3(128, 3), 256, 0, stream>>>(img, c4w1, c4a, part_c4, 3, 256, 256);
    ln_apply_k<<<21 * 256, 256, 0, stream>>>(c4a, part_c4, c4g1, c4b1, 65536, 128, 1.f / 65536.f);
    conv2_k<7><<<dim3(128, 6), 256, 0, stream>>>(c4a, c4w2, c4bb, part_c4, 21, 256, 256);
    ln_apply_k<<<42 * 256, 256, 0, stream>>>(c4bb, part_c4, c4g2, c4b2, 65536, 128, 1.f / 65536.f);
    apool3_k<<<42 * 9, 256, 0, stream>>>(c4bb, gfc, 256, 256, 0);

    // argmin AFTER apool(c4): scratch overlaps the now-dead c4bb region
    vprep_k<<<25, 64, 0, stream>>>(vert, vert4);
    argmin_part_k<<<dim3(NQ_ / 256, VSPLIT), 256, 0, stream>>>(v, vert4, bestd, besti);
    argmin_comb_k<<<NQ_ / 256, 256, 0, stream>>>(bestd, besti, idx);

    // global-token conv1d stack -> vf cols 11..28
    gt1_k<<<779, 64, 0, stream>>>(gfc, gtw1, gtg1, gtb1, gth);
    gt2_k<<<1558, 256, 0, stream>>>(gth, gtw2, gtg2, gtb2, vfb);

    // fused per-query MFMA MLP path
    mlp_mfma_k<<<NQ_ / 64, 256, 0, stream>>>(idx, vvis, qvis, ixy, ft_xy, lat, vfb,
                                             wbf, out);
}

// Round 7
// 423.336 us; speedup vs baseline: 1.4951x; 1.4951x over previous
//
#include <hip/hip_runtime.h>
#include <hip/hip_bf16.h>
#include <math.h>

#define NQ_    65536
#define NV_    1558
#define HALF_V 779
#define VSPLIT 8
#define VCHUNK 195   // ceil(1558/8); ranges ascending in p

// ws layout in floats (total 4,452,352 floats = 17.8 MB)
#define WS_STATS 0          //   512
#define WS_GFC   512        //   768
#define WS_GTH   1280       // 14080
#define WS_VF    15360      // 50176 (1558*32)
#define WS_C3A   65536      // 86016  (reused: bf16 weights after c3 conv2)
#define WS_C3B   151552     // 172032 (tail reused for c4 stat partials)
#define WS_C4A   323584     // 1376256 (head reused for c3 stat partials)
#define WS_C4B   1699840    // 2752512 (reused after apool(c4): idx/bestd/besti/vert4)

typedef __attribute__((ext_vector_type(8))) short bf16x8;
typedef __attribute__((ext_vector_type(4))) float f32x4;
typedef float float4a __attribute__((ext_vector_type(4), aligned(4)));  // 4B-aligned float4 load

__device__ __forceinline__ short f2b(float x) {
    union { __hip_bfloat16 h; short s; } u; u.h = __float2bfloat16(x); return u.s;
}

// ---------------- bilinear feature sampling (vertices) ----------------
__device__ __forceinline__ void bsample(const float* __restrict__ f, int C, int H, int W,
                                        float xn, float yn, float* __restrict__ o) {
    float x = (xn + 1.f) * 0.5f * (float)(W - 1);
    float y = (yn + 1.f) * 0.5f * (float)(H - 1);
    float x0f = floorf(x), y0f = floorf(y);
    float wx = x - x0f, wy = y - y0f;
    int x0 = (int)fminf(fmaxf(x0f, 0.f), (float)(W - 1));
    int x1 = (int)fminf(fmaxf(x0f + 1.f, 0.f), (float)(W - 1));
    int y0 = (int)fminf(fmaxf(y0f, 0.f), (float)(H - 1));
    int y1 = (int)fminf(fmaxf(y0f + 1.f, 0.f), (float)(H - 1));
    for (int c = 0; c < C; ++c) {
        const float* b = f + c * H * W;
        float v00 = b[y0 * W + x0], v01 = b[y0 * W + x1];
        float v10 = b[y1 * W + x0], v11 = b[y1 * W + x1];
        o[c] = v00 * (1.f - wx) * (1.f - wy) + v01 * wx * (1.f - wy)
             + v10 * (1.f - wx) * wy       + v11 * wx * wy;
    }
}

__global__ void feat_sample_k(const float* __restrict__ vert_xy,
                              const float* __restrict__ img,
                              const float* __restrict__ ft1,
                              float* __restrict__ vf) {
    int v = blockIdx.x * 64 + threadIdx.x;
    if (v >= NV_) return;
    float xn = vert_xy[v * 2 + 0], yn = vert_xy[v * 2 + 1];
    float tmp[8];
    bsample(img, 3, 256, 256, xn, yn, tmp);
    float* o = vf + v * 32;
    o[0] = tmp[0]; o[1] = tmp[1]; o[2] = tmp[2];
    bsample(ft1, 8, 64, 64, xn, yn, tmp);
    #pragma unroll
    for (int c = 0; c < 8; ++c) o[3 + c] = tmp[c];
}

// ---------------- conv2d 3x3 pad1: 2 pixels x CB channels per thread,
// ---------------- fused per-(channel,block) sum/sumsq partials ----------------
template <int CB>
__global__ __launch_bounds__(256) void conv2_k(
    const float* __restrict__ in, const float* __restrict__ w,
    float* __restrict__ out, float* __restrict__ part,
    int Cin, int H, int W) {
    int c0 = blockIdx.y * CB;
    int tid = threadIdx.x;
    int px0 = (blockIdx.x * 256 + tid) * 2;
    int HW = H * W;
    int y = px0 / W, x = px0 % W;      // x is even
    bool interior = (x > 0) && (x + 3 < W);
    float acc0[CB], acc1[CB];
    #pragma unroll
    for (int j = 0; j < CB; ++j) { acc0[j] = 0.f; acc1[j] = 0.f; }
    const float* wbase = w + c0 * Cin * 9;
    #pragma unroll 2
    for (int ci = 0; ci < Cin; ++ci) {
        const float* ip = in + ci * HW;
        float win[3][5];
        #pragma unroll
        for (int r = 0; r < 3; ++r) {
            int yy = y + r - 1;
            bool okY = (yy >= 0) && (yy < H);
            const float* rp = ip + yy * W;
            if (okY && interior) {
                // single 4B-aligned 16B load covers rp[x-1..x+2]
                float4a m4 = *(const float4a*)(rp + x - 1);
                win[r][0] = m4.x; win[r][1] = m4.y; win[r][2] = m4.z; win[r][3] = m4.w;
                win[r][4] = 0.f;
            } else if (okY) {
                win[r][0] = (x > 0) ? rp[x - 1] : 0.f;
                win[r][1] = rp[x]; win[r][2] = rp[x + 1];
                win[r][3] = (x + 2 < W) ? rp[x + 2] : 0.f;
                win[r][4] = 0.f;
            } else {
                win[r][0] = win[r][1] = win[r][2] = win[r][3] = win[r][4] = 0.f;
            }
        }
        const float* wc = wbase + ci * 9;
        #pragma unroll
        for (int j = 0; j < CB; ++j) {
            const float* wj = wc + j * Cin * 9;
            #pragma unroll
            for (int r = 0; r < 3; ++r) {
                float w0 = wj[r * 3 + 0], w1 = wj[r * 3 + 1], w2 = wj[r * 3 + 2];
                acc0[j] = fmaf(w0, win[r][0], fmaf(w1, win[r][1], fmaf(w2, win[r][2], acc0[j])));
                acc1[j] = fmaf(w0, win[r][1], fmaf(w1, win[r][2], fmaf(w2, win[r][3], acc1[j])));
            }
        }
    }
    #pragma unroll
    for (int j = 0; j < CB; ++j)
        *(float2*)(out + (c0 + j) * HW + px0) = make_float2(acc0[j], acc1[j]);

    // fused stats: per-(channel, block) sum / sumsq
    __shared__ float sred[4][CB][2];
    int lane = tid & 63, wave = tid >> 6;
    #pragma unroll
    for (int j = 0; j < CB; ++j) {
        float s = acc0[j] + acc1[j];
        float qq = acc0[j] * acc0[j] + acc1[j] * acc1[j];
        #pragma unroll
        for (int off = 1; off < 64; off <<= 1) {
            s  += __shfl_xor(s, off, 64);
            qq += __shfl_xor(qq, off, 64);
        }
        if (lane == 0) { sred[wave][j][0] = s; sred[wave][j][1] = qq; }
    }
    __syncthreads();
    if (tid < CB) {
        float s = sred[0][tid][0] + sred[1][tid][0] + sred[2][tid][0] + sred[3][tid][0];
        float qq = sred[0][tid][1] + sred[1][tid][1] + sred[2][tid][1] + sred[3][tid][1];
        int c = c0 + tid;
        part[(c * gridDim.x + blockIdx.x) * 2 + 0] = s;
        part[(c * gridDim.x + blockIdx.x) * 2 + 1] = qq;
    }
}

// ---------------- reduce per-block partials -> per-channel (mean, rsqrt(var)) ----------------
__global__ void ln_finalize_k(const float* __restrict__ part, float* __restrict__ stats,
                              int C, int nb, float invHW) {
    int c = threadIdx.x;
    if (c >= C) return;
    float s = 0.f, s2 = 0.f;
    for (int i = 0; i < nb; ++i) {
        s  += part[(c * nb + i) * 2 + 0];
        s2 += part[(c * nb + i) * 2 + 1];
    }
    float m = s * invHW;
    float var = s2 * invHW - m * m;
    if (var < 0.f) var = 0.f;
    stats[c * 2 + 0] = m;
    stats[c * 2 + 1] = rsqrtf(var + 1e-6f);
}

// ---------------- LN apply (+relu): 2 stat loads per thread ----------------
__global__ __launch_bounds__(256) void ln_apply_k(
    float* __restrict__ buf, const float* __restrict__ stats,
    const float* __restrict__ g, const float* __restrict__ b, int HW) {
    int i = blockIdx.x * 256 + threadIdx.x;
    int c = i / HW;      // HW is a power of two
    int hw = i % HW;
    float m = stats[c * 2], inv = stats[c * 2 + 1];
    float x = buf[i];
    float r = fmaf((x - m) * inv, g[hw], b[hw]);
    buf[i] = fmaxf(r, 0.f);
}

// ---------------- adaptive 3x3 avg pool -> gf_cat[c][colOff + bin] ----------------
__global__ __launch_bounds__(256) void apool3_k(const float* __restrict__ in,
                                                float* __restrict__ gfc,
                                                int H, int W, int colOff) {
    int c = (int)blockIdx.x / 9;
    int bin = (int)blockIdx.x % 9;
    int bh = bin / 3, bw = bin % 3;
    int hs = bh * H / 3, he = ((bh + 1) * H + 2) / 3;
    int wsx = bw * W / 3, we = ((bw + 1) * W + 2) / 3;
    int rw = we - wsx, rh = he - hs, n = rw * rh;
    const float* b = in + c * H * W;
    float s = 0.f;
    for (int t = threadIdx.x; t < n; t += 256) {
        int iy = t / rw, ix = t % rw;
        s += b[(hs + iy) * W + (wsx + ix)];
    }
    __shared__ float rs[256];
    rs[threadIdx.x] = s;
    __syncthreads();
    for (int st = 128; st > 0; st >>= 1) {
        if (threadIdx.x < st) rs[threadIdx.x] += rs[threadIdx.x + st];
        __syncthreads();
    }
    if (threadIdx.x == 0) gfc[c * 18 + colOff + bin] = rs[0] / (float)n;
}

// ---------------- conv1d (42->779) + LN(18) + relu ----------------
__global__ __launch_bounds__(64) void gt1_k(const float* __restrict__ gfc,
                                            const float* __restrict__ w,
                                            const float* __restrict__ g,
                                            const float* __restrict__ b,
                                            float* __restrict__ outh) {
    int o = blockIdx.x;     // 779
    int p = threadIdx.x;
    __shared__ float vals[18];
    if (p < 18) {
        float acc = 0.f;
        const float* wo = w + o * 42 * 3;
        for (int c = 0; c < 42; ++c) {
            const float* gr = gfc + c * 18;
            #pragma unroll
            for (int k = 0; k < 3; ++k) {
                int pk = p + k - 1;
                if (pk >= 0 && pk < 18) acc = fmaf(wo[c * 3 + k], gr[pk], acc);
            }
        }
        vals[p] = acc;
    }
    __syncthreads();
    if (p < 18) {
        float s = 0.f, s2 = 0.f;
        #pragma unroll
        for (int j = 0; j < 18; ++j) { float x = vals[j]; s += x; s2 += x * x; }
        float m = s / 18.f;
        float var = s2 / 18.f - m * m;
        if (var < 0.f) var = 0.f;
        float inv = rsqrtf(var + 1e-6f);
        float r = fmaf((vals[p] - m) * inv, g[p], b[p]);
        outh[o * 18 + p] = fmaxf(r, 0.f);
    }
}

// ---------------- conv1d (779->1558) + LN(18) + relu -> vf cols 11..28 ----------------
// 4 waves per block; each wave covers a contiguous quarter of the 779 channels.
__global__ __launch_bounds__(256) void gt2_k(const float* __restrict__ h,
                                             const float* __restrict__ w,
                                             const float* __restrict__ g,
                                             const float* __restrict__ b,
                                             float* __restrict__ vf) {
    int o = blockIdx.x;     // 1558
    int t = threadIdx.x, lane = t & 63, wave = t >> 6;
    __shared__ float red[4][18];
    float part[18];
    #pragma unroll
    for (int p = 0; p < 18; ++p) part[p] = 0.f;
    int c0 = wave * 195;
    int c1 = c0 + 195; if (c1 > HALF_V) c1 = HALF_V;
    for (int c = c0 + lane; c < c1; c += 64) {
        const float* wr = w + (o * HALF_V + c) * 3;
        float w0 = wr[0], w1 = wr[1], w2 = wr[2];
        const float* hr = h + c * 18;
        float hv[18];
        #pragma unroll
        for (int p = 0; p < 18; ++p) hv[p] = hr[p];
        #pragma unroll
        for (int p = 0; p < 18; ++p) {
            float a = w1 * hv[p];
            if (p > 0)  a = fmaf(w0, hv[p - 1], a);
            if (p < 17) a = fmaf(w2, hv[p + 1], a);
            part[p] += a;
        }
    }
    #pragma unroll
    for (int p = 0; p < 18; ++p) {
        float vv = part[p];
        #pragma unroll
        for (int off = 32; off > 0; off >>= 1) vv += __shfl_xor(vv, off, 64);
        part[p] = vv;
    }
    if (lane == 0) {
        #pragma unroll
        for (int p = 0; p < 18; ++p) red[wave][p] = part[p];
    }
    __syncthreads();
    if (t < 18) {
        float s = red[0][t] + red[1][t] + red[2][t] + red[3][t];
        red[0][t] = s;
    }
    __syncthreads();
    if (t < 18) {
        float s = 0.f, s2 = 0.f;
        #pragma unroll
        for (int j = 0; j < 18; ++j) { float x = red[0][j]; s += x; s2 += x * x; }
        float m = s / 18.f;
        float var = s2 / 18.f - m * m;
        if (var < 0.f) var = 0.f;
        float inv = rsqrtf(var + 1e-6f);
        float r = fmaf((red[0][t] - m) * inv, g[t], b[t]);
        vf[o * 32 + 11 + t] = fmaxf(r, 0.f);
    }
}

// ---------------- argmin: one THREAD per query, wave-uniform vertex scan ----------------
__global__ void vprep_k(const float* __restrict__ vert, float4* __restrict__ v4) {
    int i = blockIdx.x * 64 + threadIdx.x;
    if (i >= NV_) return;
    float x = vert[i * 3 + 0], y = vert[i * 3 + 1], z = vert[i * 3 + 2];
    float pn = __fadd_rn(__fadd_rn(__fmul_rn(x, x), __fmul_rn(y, y)), __fmul_rn(z, z));
    v4[i] = make_float4(x, y, z, pn);
}

__global__ __launch_bounds__(256) void argmin_part_k(
    const float* __restrict__ v, const float4* __restrict__ v4,
    float* __restrict__ bestd, int* __restrict__ besti) {
    int q = blockIdx.x * 256 + threadIdx.x;
    int r = blockIdx.y;
    int p0 = r * VCHUNK;
    int p1 = p0 + VCHUNK; if (p1 > NV_) p1 = NV_;
    float vx = v[q * 3 + 0], vy = v[q * 3 + 1], vz = v[q * 3 + 2];
    float vn = __fadd_rn(__fadd_rn(__fmul_rn(vx, vx), __fmul_rn(vy, vy)), __fmul_rn(vz, vz));
    float best = 3.4e38f;
    int bi = p0;
    // d2 = (|v|^2 + |p|^2) - 2*(v.p); np rounding preserved (no fma contraction).
    // v4[p] is wave-uniform -> scalar K$ loads; strict < keeps smallest p on ties.
    #pragma unroll 4
    for (int p = p0; p < p1; ++p) {
        float4 pv = v4[p];
        float dot = __fadd_rn(__fadd_rn(__fmul_rn(vx, pv.x), __fmul_rn(vy, pv.y)), __fmul_rn(vz, pv.z));
        float d2 = __fsub_rn(__fadd_rn(vn, pv.w), __fmul_rn(2.f, dot));
        if (d2 < best) { best = d2; bi = p; }
    }
    bestd[r * NQ_ + q] = best;
    besti[r * NQ_ + q] = bi;
}

__global__ __launch_bounds__(256) void argmin_comb_k(
    const float* __restrict__ bestd, const int* __restrict__ besti,
    int* __restrict__ idx) {
    int q = blockIdx.x * 256 + threadIdx.x;
    float best = bestd[q];
    int bi = besti[q];
    #pragma unroll
    for (int r = 1; r < VSPLIT; ++r) {
        float d = bestd[r * NQ_ + q];
        int i2 = besti[r * NQ_ + q];
        if (d < best) { best = d; bi = i2; }   // ranges ascend in p; strict < keeps first min
    }
    idx[q] = bi;
}

// ---------------- weight f32 -> bf16 (with row zero-padding) ----------------
// wb layout (shorts): [0,9216) atw1 ; [9216,10752) atw2 pad to 16 rows ;
//                     [10752,19968) fcw1 ; [19968,24576) fcw2 pad to 48 rows
__global__ void wcvt_k(const float* __restrict__ atw1, const float* __restrict__ atw2,
                       const float* __restrict__ fcw1, const float* __restrict__ fcw2,
                       short* __restrict__ wb) {
    int i = blockIdx.x * 256 + threadIdx.x;   // grid 96 -> 24576
    short v = 0;
    if (i < 9216) v = f2b(atw1[i]);
    else if (i < 10752) { int j = i - 9216; v = (j < 576) ? f2b(atw2[j]) : (short)0; }
    else if (i < 19968) v = f2b(fcw1[i - 10752]);
    else { int j = i - 19968; v = (j < 3840) ? f2b(fcw2[j]) : (short)0; }
    wb[i] = v;
}

// ---------------- MFMA MLP: 16 queries per wave, 64 per block ----------------
#define YP 104   // padded LDS row stride in shorts (2-way bank aliasing only)

__global__ __launch_bounds__(256) void mlp_mfma_k(
    const int* __restrict__ idx,
    const float* __restrict__ vvis, const float* __restrict__ qvis,
    const float* __restrict__ ixy, const float* __restrict__ fxy,
    const float* __restrict__ lat, const float* __restrict__ vf,
    const short* __restrict__ wb, float* __restrict__ out) {
    __shared__ short Y[64 * YP];
    __shared__ short Hb[64 * YP];
    __shared__ float A6[64 * 8];
    int t = threadIdx.x;
    int lane = t & 63, wave = t >> 6;
    int q0 = blockIdx.x * 64;

    // ---- y build: 4 lanes per query, bf16 into LDS; keep f32 copy in regs ----
    int ql = t >> 2, part = t & 3;
    int q = q0 + ql;
    int bi = idx[q];
    int bi2 = bi + HALF_V; if (bi2 >= NV_) bi2 -= NV_;
    const float* f  = vf + bi * 32;
    const float* ft = vf + bi2 * 32;
    float vis = vvis[bi], vist = vvis[bi2];
    short* yr = &Y[ql * YP];
    float myv[24];
    #pragma unroll
    for (int jj = 0; jj < 24; ++jj) {
        int j = part * 24 + jj;
        float val;
        if (j < 3)       val = ixy[q * 3 + j];
        else if (j < 11) val = fxy[q * 8 + j - 3];
        else if (j < 22) val = f[j - 11] * vis;
        else if (j < 33) val = ft[j - 22] * vist;
        else if (j < 51) val = f[11 + j - 33] * vis;
        else if (j < 69) val = ft[11 + j - 51] * vist;
        else if (j < 93) val = lat[q * 24 + j - 69];
        else if (j == 93) val = qvis[q];
        else if (j == 94) val = vis;
        else              val = vist;
        myv[jj] = val;
        yr[j] = f2b(val);
    }
    __syncthreads();

    int nloc = lane & 15, quad = lane >> 4;
    const short* Ya = &Y[(wave * 16 + nloc) * YP];
    const short* Ha = &Hb[(wave * 16 + nloc) * YP];
    int hrow = wave * 16 + quad * 4;    // C-layout row base for this lane

    // ---- GEMM1: H = relu(Y x atw1^T) ----
    f32x4 acc[6];
    #pragma unroll
    for (int nt = 0; nt < 6; ++nt) acc[nt] = (f32x4){0.f, 0.f, 0.f, 0.f};
    #pragma unroll
    for (int k0 = 0; k0 < 96; k0 += 32) {
        bf16x8 a = *(const bf16x8*)(Ya + k0 + quad * 8);
        #pragma unroll
        for (int nt = 0; nt < 6; ++nt) {
            bf16x8 b = *(const bf16x8*)(wb + (nt * 16 + nloc) * 96 + k0 + quad * 8);
            acc[nt] = __builtin_amdgcn_mfma_f32_16x16x32_bf16(a, b, acc[nt], 0, 0, 0);
        }
    }
    #pragma unroll
    for (int nt = 0; nt < 6; ++nt)
        #pragma unroll
        for (int r = 0; r < 4; ++r)
            Hb[(hrow + r) * YP + nt * 16 + nloc] = f2b(fmaxf(acc[nt][r], 0.f));
    __syncthreads();

    // ---- GEMM2: at6 = sigmoid(H x atw2^T) ----
    {
        const short* w2 = wb + 9216;
        f32x4 a2 = (f32x4){0.f, 0.f, 0.f, 0.f};
        #pragma unroll
        for (int k0 = 0; k0 < 96; k0 += 32) {
            bf16x8 a = *(const bf16x8*)(Ha + k0 + quad * 8);
            bf16x8 b = *(const bf16x8*)(w2 + nloc * 96 + k0 + quad * 8);
            a2 = __builtin_amdgcn_mfma_f32_16x16x32_bf16(a, b, a2, 0, 0, 0);
        }
        if (nloc < 6) {
            #pragma unroll
            for (int r = 0; r < 4; ++r)
                A6[(hrow + r) * 8 + nloc] = 1.f / (1.f + expf(-a2[r]));
        }
    }
    __syncthreads();

    // ---- scale Y in place from f32 register copy ----
    {
        const float* ap = &A6[ql * 8];
        #pragma unroll
        for (int jj = 0; jj < 24; ++jj) {
            int j = part * 24 + jj;
            float s;
            if (j < 11)      s = ap[0];
            else if (j < 22) s = ap[1];
            else if (j < 33) s = ap[2];
            else if (j < 51) s = ap[3];
            else if (j < 69) s = ap[4];
            else if (j < 93) s = ap[5];
            else             s = 1.f;
            yr[j] = f2b(myv[jj] * s);
        }
    }
    __syncthreads();

    // ---- GEMM3: H2 = relu(Y2 x fcw1^T) ----
    {
        const short* w3 = wb + 10752;
        #pragma unroll
        for (int nt = 0; nt < 6; ++nt) acc[nt] = (f32x4){0.f, 0.f, 0.f, 0.f};
        #pragma unroll
        for (int k0 = 0; k0 < 96; k0 += 32) {
            bf16x8 a = *(const bf16x8*)(Ya + k0 + quad * 8);
            #pragma unroll
            for (int nt = 0; nt < 6; ++nt) {
                bf16x8 b = *(const bf16x8*)(w3 + (nt * 16 + nloc) * 96 + k0 + quad * 8);
                acc[nt] = __builtin_amdgcn_mfma_f32_16x16x32_bf16(a, b, acc[nt], 0, 0, 0);
            }
        }
        #pragma unroll
        for (int nt = 0; nt < 6; ++nt)
            #pragma unroll
            for (int r = 0; r < 4; ++r)
                Hb[(hrow + r) * YP + nt * 16 + nloc] = f2b(fmaxf(acc[nt][r], 0.f));
    }
    __syncthreads();

    // ---- GEMM4: OUT = H2 x fcw2^T ----
    {
        const short* w4 = wb + 19968;
        f32x4 oacc[3];
        #pragma unroll
        for (int nt = 0; nt < 3; ++nt) oacc[nt] = (f32x4){0.f, 0.f, 0.f, 0.f};
        #pragma unroll
        for (int k0 = 0; k0 < 96; k0 += 32) {
            bf16x8 a = *(const bf16x8*)(Ha + k0 + quad * 8);
            #pragma unroll
            for (int nt = 0; nt < 3; ++nt) {
                bf16x8 b = *(const bf16x8*)(w4 + (nt * 16 + nloc) * 96 + k0 + quad * 8);
                oacc[nt] = __builtin_amdgcn_mfma_f32_16x16x32_bf16(a, b, oacc[nt], 0, 0, 0);
            }
        }
        #pragma unroll
        for (int nt = 0; nt < 3; ++nt) {
            int oc = nt * 16 + nloc;
            if (oc < 40) {
                #pragma unroll
                for (int r = 0; r < 4; ++r)
                    out[(q0 + hrow + r) * 40 + oc] = oacc[nt][r];
            }
        }
    }
}

extern "C" void kernel_launch(void* const* d_in, const int* in_sizes, int n_in,
                              void* d_out, int out_size, void* d_ws, size_t ws_size,
                              hipStream_t stream) {
    const float* vert_xy = (const float*)d_in[0];
    const float* ft1     = (const float*)d_in[1];
    const float* ft_xy   = (const float*)d_in[2];
    const float* vert    = (const float*)d_in[3];
    const float* v       = (const float*)d_in[4];
    const float* vvis    = (const float*)d_in[5];
    const float* qvis    = (const float*)d_in[6];
    const float* ixy     = (const float*)d_in[7];
    const float* img     = (const float*)d_in[8];
    const float* lat     = (const float*)d_in[9];
    const float* fcw1    = (const float*)d_in[10];
    const float* fcw2    = (const float*)d_in[11];
    const float* atw1    = (const float*)d_in[12];
    const float* atw2    = (const float*)d_in[13];
    const float* gtw1    = (const float*)d_in[14];
    const float* gtg1    = (const float*)d_in[15];
    const float* gtb1    = (const float*)d_in[16];
    const float* gtw2    = (const float*)d_in[17];
    const float* gtg2    = (const float*)d_in[18];
    const float* gtb2    = (const float*)d_in[19];
    const float* c3w1    = (const float*)d_in[20];
    const float* c3g1    = (const float*)d_in[21];
    const float* c3b1    = (const float*)d_in[22];
    const float* c3w2    = (const float*)d_in[23];
    const float* c3g2    = (const float*)d_in[24];
    const float* c3b2    = (const float*)d_in[25];
    const float* c4w1    = (const float*)d_in[26];
    const float* c4g1    = (const float*)d_in[27];
    const float* c4b1    = (const float*)d_in[28];
    const float* c4w2    = (const float*)d_in[29];
    const float* c4g2    = (const float*)d_in[30];
    const float* c4b2    = (const float*)d_in[31];
    float* out = (float*)d_out;
    float* ws  = (float*)d_ws;
    float* stats = ws + WS_STATS;
    float* gfc   = ws + WS_GFC;
    float* gth   = ws + WS_GTH;
    float* vfb   = ws + WS_VF;
    float* c3a   = ws + WS_C3A;
    float* c3bb  = ws + WS_C3B;
    float* c4a   = ws + WS_C4A;
    float* c4bb  = ws + WS_C4B;
    float* part_c3 = ws + WS_C4A;            // c4a not live during c3 chain
    short* wbf     = (short*)(ws + WS_C3A);  // c3a dead after c3 conv2 (24576 shorts)
    float* part_c4 = ws + WS_C3B;            // c3bb dead after apool(c3)
    // after apool(c4), c4bb region is dead; carve argmin scratch out of it:
    int*    idx   = (int*)(ws + WS_C4B);                     // 65536 ints
    float*  bestd = ws + WS_C4B + 65536;                     // 8*65536 floats
    int*    besti = (int*)(ws + WS_C4B + 65536 + 524288);    // 8*65536 ints
    float4* vert4 = (float4*)(ws + WS_C4B + 65536 + 1048576); // 1558 float4

    feat_sample_k<<<25, 64, 0, stream>>>(vert_xy, img, ft1, vfb);

    // c3 chain: ft1 (8,64,64) -> (21) -> (42) -> pool -> gfc cols 9..17
    conv2_k<7><<<dim3(8, 3), 256, 0, stream>>>(ft1, c3w1, c3a, part_c3, 8, 64, 64);
    ln_finalize_k<<<1, 64, 0, stream>>>(part_c3, stats + 0, 21, 8, 1.f / 4096.f);
    ln_apply_k<<<21 * 16, 256, 0, stream>>>(c3a, stats + 0, c3g1, c3b1, 4096);
    conv2_k<7><<<dim3(8, 6), 256, 0, stream>>>(c3a, c3w2, c3bb, part_c3, 21, 64, 64);
    wcvt_k<<<96, 256, 0, stream>>>(atw1, atw2, fcw1, fcw2, wbf);  // c3a now dead
    ln_finalize_k<<<1, 64, 0, stream>>>(part_c3, stats + 128, 42, 8, 1.f / 4096.f);
    ln_apply_k<<<42 * 16, 256, 0, stream>>>(c3bb, stats + 128, c3g2, c3b2, 4096);
    apool3_k<<<42 * 9, 256, 0, stream>>>(c3bb, gfc, 64, 64, 9);

    // c4 chain: img (3,256,256) -> (21) -> (42) -> pool -> gfc cols 0..8
    conv2_k<7><<<dim3(128, 3), 256, 0, stream>>>(img, c4w1, c4a, part_c4, 3, 256, 256);
    ln_finalize_k<<<1, 64, 0, stream>>>(part_c4, stats + 256, 21, 128, 1.f / 65536.f);
    ln_apply_k<<<21 * 256, 256, 0, stream>>>(c4a, stats + 256, c4g1, c4b1, 65536);
    conv2_k<7><<<dim3(128, 6), 256, 0, stream>>>(c4a, c4w2, c4bb, part_c4, 21, 256, 256);
    ln_finalize_k<<<1, 64, 0, stream>>>(part_c4, stats + 384, 42, 128, 1.f / 65536.f);
    ln_apply_k<<<42 * 256, 256, 0, stream>>>(c4bb, stats + 384, c4g2, c4b2, 65536);
    apool3_k<<<42 * 9, 256, 0, stream>>>(c4bb, gfc, 256, 256, 0);

    // argmin AFTER apool(c4): scratch overlaps the now-dead c4bb region
    vprep_k<<<25, 64, 0, stream>>>(vert, vert4);
    argmin_part_k<<<dim3(NQ_ / 256, VSPLIT), 256, 0, stream>>>(v, vert4, bestd, besti);
    argmin_comb_k<<<NQ_ / 256, 256, 0, stream>>>(bestd, besti, idx);

    // global-token conv1d stack -> vf cols 11..28
    gt1_k<<<779, 64, 0, stream>>>(gfc, gtw1, gtg1, gtb1, gth);
    gt2_k<<<1558, 256, 0, stream>>>(gth, gtw2, gtg2, gtb2, vfb);

    // fused per-query MFMA MLP path
    mlp_mfma_k<<<NQ_ / 64, 256, 0, stream>>>(idx, vvis, qvis, ixy, ft_xy, lat, vfb,
                                             wbf, out);
}

// Round 8
// 381.103 us; speedup vs baseline: 1.6608x; 1.1108x over previous
//
#include <hip/hip_runtime.h>
#include <hip/hip_bf16.h>
#include <math.h>

#define NQ_    65536
#define NV_    1558
#define HALF_V 779
#define VSPLIT 8
#define VCHUNK 195   // ceil(1558/8); ranges ascending in p

// ws layout in floats (total 4,452,352 floats = 17.8 MB)
#define WS_STATS 0          //   512
#define WS_GFC   512        //   768
#define WS_GTH   1280       // 14080
#define WS_VF    15360      // 50176 (1558*32)
#define WS_C3A   65536      // 86016  (reused: bf16 weights after c3 conv2)
#define WS_C3B   151552     // 172032 (tail reused for c4 stat partials)
#define WS_C4A   323584     // 1376256 (head reused for c3 stat partials)
#define WS_C4B   1699840    // 2752512 (reused after apool(c4): idx/bestd/besti/vert4)

typedef __attribute__((ext_vector_type(8))) short bf16x8;
typedef __attribute__((ext_vector_type(4))) float f32x4;

__device__ __forceinline__ short f2b(float x) {
    union { __hip_bfloat16 h; short s; } u; u.h = __float2bfloat16(x); return u.s;
}

// ---------------- bilinear feature sampling (vertices) ----------------
__device__ __forceinline__ void bsample(const float* __restrict__ f, int C, int H, int W,
                                        float xn, float yn, float* __restrict__ o) {
    float x = (xn + 1.f) * 0.5f * (float)(W - 1);
    float y = (yn + 1.f) * 0.5f * (float)(H - 1);
    float x0f = floorf(x), y0f = floorf(y);
    float wx = x - x0f, wy = y - y0f;
    int x0 = (int)fminf(fmaxf(x0f, 0.f), (float)(W - 1));
    int x1 = (int)fminf(fmaxf(x0f + 1.f, 0.f), (float)(W - 1));
    int y0 = (int)fminf(fmaxf(y0f, 0.f), (float)(H - 1));
    int y1 = (int)fminf(fmaxf(y0f + 1.f, 0.f), (float)(H - 1));
    for (int c = 0; c < C; ++c) {
        const float* b = f + c * H * W;
        float v00 = b[y0 * W + x0], v01 = b[y0 * W + x1];
        float v10 = b[y1 * W + x0], v11 = b[y1 * W + x1];
        o[c] = v00 * (1.f - wx) * (1.f - wy) + v01 * wx * (1.f - wy)
             + v10 * (1.f - wx) * wy       + v11 * wx * wy;
    }
}

__global__ void feat_sample_k(const float* __restrict__ vert_xy,
                              const float* __restrict__ img,
                              const float* __restrict__ ft1,
                              float* __restrict__ vf) {
    int v = blockIdx.x * 64 + threadIdx.x;
    if (v >= NV_) return;
    float xn = vert_xy[v * 2 + 0], yn = vert_xy[v * 2 + 1];
    float tmp[8];
    bsample(img, 3, 256, 256, xn, yn, tmp);
    float* o = vf + v * 32;
    o[0] = tmp[0]; o[1] = tmp[1]; o[2] = tmp[2];
    bsample(ft1, 8, 64, 64, xn, yn, tmp);
    #pragma unroll
    for (int c = 0; c < 8; ++c) o[3 + c] = tmp[c];
}

// ---------------- conv2d 3x3 pad1: 4 pixels x CB channels per thread,
// ---------------- aligned float4 row loads, fused per-(channel,block) stats ----------------
template <int CB>
__global__ __launch_bounds__(256) void conv4_k(
    const float* __restrict__ in, const float* __restrict__ w,
    float* __restrict__ out, float* __restrict__ part,
    int Cin, int H, int W) {
    int c0 = blockIdx.y * CB;
    int tid = threadIdx.x;
    int px0 = (blockIdx.x * 256 + tid) * 4;
    int HW = H * W;
    int y = px0 / W, x = px0 % W;      // x is a multiple of 4
    float acc[CB][4];
    #pragma unroll
    for (int j = 0; j < CB; ++j)
        #pragma unroll
        for (int p = 0; p < 4; ++p) acc[j][p] = 0.f;
    const float* wbase = w + c0 * Cin * 9;
    #pragma unroll 2
    for (int ci = 0; ci < Cin; ++ci) {
        const float* ip = in + ci * HW;
        float win[3][6];
        #pragma unroll
        for (int r = 0; r < 3; ++r) {
            int yy = y + r - 1;
            bool okY = (yy >= 0) && (yy < H);
            const float* rp = ip + yy * W;
            if (okY) {
                float4 m4 = *(const float4*)(rp + x);   // 16B-aligned
                win[r][1] = m4.x; win[r][2] = m4.y; win[r][3] = m4.z; win[r][4] = m4.w;
                win[r][0] = (x > 0)     ? rp[x - 1] : 0.f;
                win[r][5] = (x + 4 < W) ? rp[x + 4] : 0.f;
            } else {
                #pragma unroll
                for (int k = 0; k < 6; ++k) win[r][k] = 0.f;
            }
        }
        const float* wc = wbase + ci * 9;
        #pragma unroll
        for (int j = 0; j < CB; ++j) {
            const float* wj = wc + j * Cin * 9;   // wave-uniform -> scalar loads
            #pragma unroll
            for (int r = 0; r < 3; ++r) {
                float w0 = wj[r * 3 + 0], w1 = wj[r * 3 + 1], w2 = wj[r * 3 + 2];
                #pragma unroll
                for (int p = 0; p < 4; ++p)
                    acc[j][p] = fmaf(w0, win[r][p],
                                fmaf(w1, win[r][p + 1],
                                fmaf(w2, win[r][p + 2], acc[j][p])));
            }
        }
    }
    #pragma unroll
    for (int j = 0; j < CB; ++j) {
        float4 o4 = make_float4(acc[j][0], acc[j][1], acc[j][2], acc[j][3]);
        *(float4*)(out + (c0 + j) * HW + px0) = o4;
    }

    // fused stats: per-(channel, block) sum / sumsq
    __shared__ float sred[4][CB][2];
    int lane = tid & 63, wave = tid >> 6;
    #pragma unroll
    for (int j = 0; j < CB; ++j) {
        float s  = acc[j][0] + acc[j][1] + acc[j][2] + acc[j][3];
        float qq = acc[j][0] * acc[j][0] + acc[j][1] * acc[j][1]
                 + acc[j][2] * acc[j][2] + acc[j][3] * acc[j][3];
        #pragma unroll
        for (int off = 1; off < 64; off <<= 1) {
            s  += __shfl_xor(s, off, 64);
            qq += __shfl_xor(qq, off, 64);
        }
        if (lane == 0) { sred[wave][j][0] = s; sred[wave][j][1] = qq; }
    }
    __syncthreads();
    if (tid < CB) {
        float s  = sred[0][tid][0] + sred[1][tid][0] + sred[2][tid][0] + sred[3][tid][0];
        float qq = sred[0][tid][1] + sred[1][tid][1] + sred[2][tid][1] + sred[3][tid][1];
        int c = c0 + tid;
        part[(c * gridDim.x + blockIdx.x) * 2 + 0] = s;
        part[(c * gridDim.x + blockIdx.x) * 2 + 1] = qq;
    }
}

// ---------------- reduce per-block partials -> per-channel (mean, rsqrt(var)) ----------------
__global__ void ln_finalize_k(const float* __restrict__ part, float* __restrict__ stats,
                              int C, int nb, float invHW) {
    int c = threadIdx.x;
    if (c >= C) return;
    float s = 0.f, s2 = 0.f;
    for (int i = 0; i < nb; ++i) {
        s  += part[(c * nb + i) * 2 + 0];
        s2 += part[(c * nb + i) * 2 + 1];
    }
    float m = s * invHW;
    float var = s2 * invHW - m * m;
    if (var < 0.f) var = 0.f;
    stats[c * 2 + 0] = m;
    stats[c * 2 + 1] = rsqrtf(var + 1e-6f);
}

// ---------------- LN apply (+relu): 2 stat loads per thread (feeds next conv) ----------------
__global__ __launch_bounds__(256) void ln_apply_k(
    float* __restrict__ buf, const float* __restrict__ stats,
    const float* __restrict__ g, const float* __restrict__ b, int HW) {
    int i = blockIdx.x * 256 + threadIdx.x;
    int c = i / HW;      // HW is a power of two
    int hw = i % HW;
    float m = stats[c * 2], inv = stats[c * 2 + 1];
    float x = buf[i];
    float r = fmaf((x - m) * inv, g[hw], b[hw]);
    buf[i] = fmaxf(r, 0.f);
}

// ---------------- adaptive 3x3 avg pool of relu(LN(x)), no materialization ----------------
__global__ __launch_bounds__(256) void apool3ln_k(
    const float* __restrict__ in, const float* __restrict__ stats,
    const float* __restrict__ g, const float* __restrict__ b,
    float* __restrict__ gfc, int H, int W, int colOff) {
    int c = (int)blockIdx.x / 9;
    int bin = (int)blockIdx.x % 9;
    int bh = bin / 3, bw = bin % 3;
    int hs = bh * H / 3, he = ((bh + 1) * H + 2) / 3;
    int wsx = bw * W / 3, we = ((bw + 1) * W + 2) / 3;
    int rw = we - wsx, rh = he - hs, n = rw * rh;
    const float* bb = in + c * H * W;
    float m = stats[c * 2], inv = stats[c * 2 + 1];   // c uniform per block -> scalar
    float s = 0.f;
    for (int t = threadIdx.x; t < n; t += 256) {
        int iy = t / rw, ix = t % rw;
        int hw = (hs + iy) * W + (wsx + ix);
        float x = bb[hw];
        float r = fmaf((x - m) * inv, g[hw], b[hw]);  // bit-identical to ln_apply->apool
        s += fmaxf(r, 0.f);
    }
    __shared__ float rs[256];
    rs[threadIdx.x] = s;
    __syncthreads();
    for (int st = 128; st > 0; st >>= 1) {
        if (threadIdx.x < st) rs[threadIdx.x] += rs[threadIdx.x + st];
        __syncthreads();
    }
    if (threadIdx.x == 0) gfc[c * 18 + colOff + bin] = rs[0] / (float)n;
}

// ---------------- conv1d (42->779) + LN(18) + relu ----------------
__global__ __launch_bounds__(64) void gt1_k(const float* __restrict__ gfc,
                                            const float* __restrict__ w,
                                            const float* __restrict__ g,
                                            const float* __restrict__ b,
                                            float* __restrict__ outh) {
    int o = blockIdx.x;     // 779
    int p = threadIdx.x;
    __shared__ float vals[18];
    if (p < 18) {
        float acc = 0.f;
        const float* wo = w + o * 42 * 3;
        for (int c = 0; c < 42; ++c) {
            const float* gr = gfc + c * 18;
            #pragma unroll
            for (int k = 0; k < 3; ++k) {
                int pk = p + k - 1;
                if (pk >= 0 && pk < 18) acc = fmaf(wo[c * 3 + k], gr[pk], acc);
            }
        }
        vals[p] = acc;
    }
    __syncthreads();
    if (p < 18) {
        float s = 0.f, s2 = 0.f;
        #pragma unroll
        for (int j = 0; j < 18; ++j) { float x = vals[j]; s += x; s2 += x * x; }
        float m = s / 18.f;
        float var = s2 / 18.f - m * m;
        if (var < 0.f) var = 0.f;
        float inv = rsqrtf(var + 1e-6f);
        float r = fmaf((vals[p] - m) * inv, g[p], b[p]);
        outh[o * 18 + p] = fmaxf(r, 0.f);
    }
}

// ---------------- conv1d (779->1558) + LN(18) + relu -> vf cols 11..28 ----------------
// 4 waves per block; each wave covers a contiguous quarter of the 779 channels.
__global__ __launch_bounds__(256) void gt2_k(const float* __restrict__ h,
                                             const float* __restrict__ w,
                                             const float* __restrict__ g,
                                             const float* __restrict__ b,
                                             float* __restrict__ vf) {
    int o = blockIdx.x;     // 1558
    int t = threadIdx.x, lane = t & 63, wave = t >> 6;
    __shared__ float red[4][18];
    float part[18];
    #pragma unroll
    for (int p = 0; p < 18; ++p) part[p] = 0.f;
    int c0 = wave * 195;
    int c1 = c0 + 195; if (c1 > HALF_V) c1 = HALF_V;
    for (int c = c0 + lane; c < c1; c += 64) {
        const float* wr = w + (o * HALF_V + c) * 3;
        float w0 = wr[0], w1 = wr[1], w2 = wr[2];
        const float* hr = h + c * 18;
        float hv[18];
        #pragma unroll
        for (int p = 0; p < 18; ++p) hv[p] = hr[p];
        #pragma unroll
        for (int p = 0; p < 18; ++p) {
            float a = w1 * hv[p];
            if (p > 0)  a = fmaf(w0, hv[p - 1], a);
            if (p < 17) a = fmaf(w2, hv[p + 1], a);
            part[p] += a;
        }
    }
    #pragma unroll
    for (int p = 0; p < 18; ++p) {
        float vv = part[p];
        #pragma unroll
        for (int off = 32; off > 0; off >>= 1) vv += __shfl_xor(vv, off, 64);
        part[p] = vv;
    }
    if (lane == 0) {
        #pragma unroll
        for (int p = 0; p < 18; ++p) red[wave][p] = part[p];
    }
    __syncthreads();
    if (t < 18) {
        float s = red[0][t] + red[1][t] + red[2][t] + red[3][t];
        red[0][t] = s;
    }
    __syncthreads();
    if (t < 18) {
        float s = 0.f, s2 = 0.f;
        #pragma unroll
        for (int j = 0; j < 18; ++j) { float x = red[0][j]; s += x; s2 += x * x; }
        float m = s / 18.f;
        float var = s2 / 18.f - m * m;
        if (var < 0.f) var = 0.f;
        float inv = rsqrtf(var + 1e-6f);
        float r = fmaf((red[0][t] - m) * inv, g[t], b[t]);
        vf[o * 32 + 11 + t] = fmaxf(r, 0.f);
    }
}

// ---------------- argmin: one THREAD per query, wave-uniform vertex scan ----------------
__global__ void vprep_k(const float* __restrict__ vert, float4* __restrict__ v4) {
    int i = blockIdx.x * 64 + threadIdx.x;
    if (i >= NV_) return;
    float x = vert[i * 3 + 0], y = vert[i * 3 + 1], z = vert[i * 3 + 2];
    float pn = __fadd_rn(__fadd_rn(__fmul_rn(x, x), __fmul_rn(y, y)), __fmul_rn(z, z));
    v4[i] = make_float4(x, y, z, pn);
}

__global__ __launch_bounds__(256) void argmin_part_k(
    const float* __restrict__ v, const float4* __restrict__ v4,
    float* __restrict__ bestd, int* __restrict__ besti) {
    int q = blockIdx.x * 256 + threadIdx.x;
    int r = blockIdx.y;
    int p0 = r * VCHUNK;
    int p1 = p0 + VCHUNK; if (p1 > NV_) p1 = NV_;
    float vx = v[q * 3 + 0], vy = v[q * 3 + 1], vz = v[q * 3 + 2];
    float vn = __fadd_rn(__fadd_rn(__fmul_rn(vx, vx), __fmul_rn(vy, vy)), __fmul_rn(vz, vz));
    float best = 3.4e38f;
    int bi = p0;
    // d2 = (|v|^2 + |p|^2) - 2*(v.p); np rounding preserved (no fma contraction).
    // v4[p] is wave-uniform -> scalar K$ loads; strict < keeps smallest p on ties.
    #pragma unroll 4
    for (int p = p0; p < p1; ++p) {
        float4 pv = v4[p];
        float dot = __fadd_rn(__fadd_rn(__fmul_rn(vx, pv.x), __fmul_rn(vy, pv.y)), __fmul_rn(vz, pv.z));
        float d2 = __fsub_rn(__fadd_rn(vn, pv.w), __fmul_rn(2.f, dot));
        if (d2 < best) { best = d2; bi = p; }
    }
    bestd[r * NQ_ + q] = best;
    besti[r * NQ_ + q] = bi;
}

__global__ __launch_bounds__(256) void argmin_comb_k(
    const float* __restrict__ bestd, const int* __restrict__ besti,
    int* __restrict__ idx) {
    int q = blockIdx.x * 256 + threadIdx.x;
    float best = bestd[q];
    int bi = besti[q];
    #pragma unroll
    for (int r = 1; r < VSPLIT; ++r) {
        float d = bestd[r * NQ_ + q];
        int i2 = besti[r * NQ_ + q];
        if (d < best) { best = d; bi = i2; }   // ranges ascend in p; strict < keeps first min
    }
    idx[q] = bi;
}

// ---------------- weight f32 -> bf16 (with row zero-padding) ----------------
// wb layout (shorts): [0,9216) atw1 ; [9216,10752) atw2 pad to 16 rows ;
//                     [10752,19968) fcw1 ; [19968,24576) fcw2 pad to 48 rows
__global__ void wcvt_k(const float* __restrict__ atw1, const float* __restrict__ atw2,
                       const float* __restrict__ fcw1, const float* __restrict__ fcw2,
                       short* __restrict__ wb) {
    int i = blockIdx.x * 256 + threadIdx.x;   // grid 96 -> 24576
    short v = 0;
    if (i < 9216) v = f2b(atw1[i]);
    else if (i < 10752) { int j = i - 9216; v = (j < 576) ? f2b(atw2[j]) : (short)0; }
    else if (i < 19968) v = f2b(fcw1[i - 10752]);
    else { int j = i - 19968; v = (j < 3840) ? f2b(fcw2[j]) : (short)0; }
    wb[i] = v;
}

// ---------------- MFMA MLP: 16 queries per wave, 64 per block ----------------
#define YP 104   // padded LDS row stride in shorts (2-way bank aliasing only)

__global__ __launch_bounds__(256) void mlp_mfma_k(
    const int* __restrict__ idx,
    const float* __restrict__ vvis, const float* __restrict__ qvis,
    const float* __restrict__ ixy, const float* __restrict__ fxy,
    const float* __restrict__ lat, const float* __restrict__ vf,
    const short* __restrict__ wb, float* __restrict__ out) {
    __shared__ short Y[64 * YP];
    __shared__ short Hb[64 * YP];
    __shared__ float A6[64 * 8];
    int t = threadIdx.x;
    int lane = t & 63, wave = t >> 6;
    int q0 = blockIdx.x * 64;

    // ---- y build: 4 lanes per query, bf16 into LDS; keep f32 copy in regs ----
    int ql = t >> 2, part = t & 3;
    int q = q0 + ql;
    int bi = idx[q];
    int bi2 = bi + HALF_V; if (bi2 >= NV_) bi2 -= NV_;
    const float* f  = vf + bi * 32;
    const float* ft = vf + bi2 * 32;
    float vis = vvis[bi], vist = vvis[bi2];
    short* yr = &Y[ql * YP];
    float myv[24];
    #pragma unroll
    for (int jj = 0; jj < 24; ++jj) {
        int j = part * 24 + jj;
        float val;
        if (j < 3)       val = ixy[q * 3 + j];
        else if (j < 11) val = fxy[q * 8 + j - 3];
        else if (j < 22) val = f[j - 11] * vis;
        else if (j < 33) val = ft[j - 22] * vist;
        else if (j < 51) val = f[11 + j - 33] * vis;
        else if (j < 69) val = ft[11 + j - 51] * vist;
        else if (j < 93) val = lat[q * 24 + j - 69];
        else if (j == 93) val = qvis[q];
        else if (j == 94) val = vis;
        else              val = vist;
        myv[jj] = val;
        yr[j] = f2b(val);
    }
    __syncthreads();

    int nloc = lane & 15, quad = lane >> 4;
    const short* Ya = &Y[(wave * 16 + nloc) * YP];
    const short* Ha = &Hb[(wave * 16 + nloc) * YP];
    int hrow = wave * 16 + quad * 4;    // C-layout row base for this lane

    // ---- GEMM1: H = relu(Y x atw1^T) ----
    f32x4 acc[6];
    #pragma unroll
    for (int nt = 0; nt < 6; ++nt) acc[nt] = (f32x4){0.f, 0.f, 0.f, 0.f};
    #pragma unroll
    for (int k0 = 0; k0 < 96; k0 += 32) {
        bf16x8 a = *(const bf16x8*)(Ya + k0 + quad * 8);
        #pragma unroll
        for (int nt = 0; nt < 6; ++nt) {
            bf16x8 b = *(const bf16x8*)(wb + (nt * 16 + nloc) * 96 + k0 + quad * 8);
            acc[nt] = __builtin_amdgcn_mfma_f32_16x16x32_bf16(a, b, acc[nt], 0, 0, 0);
        }
    }
    #pragma unroll
    for (int nt = 0; nt < 6; ++nt)
        #pragma unroll
        for (int r = 0; r < 4; ++r)
            Hb[(hrow + r) * YP + nt * 16 + nloc] = f2b(fmaxf(acc[nt][r], 0.f));
    __syncthreads();

    // ---- GEMM2: at6 = sigmoid(H x atw2^T) ----
    {
        const short* w2 = wb + 9216;
        f32x4 a2 = (f32x4){0.f, 0.f, 0.f, 0.f};
        #pragma unroll
        for (int k0 = 0; k0 < 96; k0 += 32) {
            bf16x8 a = *(const bf16x8*)(Ha + k0 + quad * 8);
            bf16x8 b = *(const bf16x8*)(w2 + nloc * 96 + k0 + quad * 8);
            a2 = __builtin_amdgcn_mfma_f32_16x16x32_bf16(a, b, a2, 0, 0, 0);
        }
        if (nloc < 6) {
            #pragma unroll
            for (int r = 0; r < 4; ++r)
                A6[(hrow + r) * 8 + nloc] = 1.f / (1.f + expf(-a2[r]));
        }
    }
    __syncthreads();

    // ---- scale Y in place from f32 register copy ----
    {
        const float* ap = &A6[ql * 8];
        #pragma unroll
        for (int jj = 0; jj < 24; ++jj) {
            int j = part * 24 + jj;
            float s;
            if (j < 11)      s = ap[0];
            else if (j < 22) s = ap[1];
            else if (j < 33) s = ap[2];
            else if (j < 51) s = ap[3];
            else if (j < 69) s = ap[4];
            else if (j < 93) s = ap[5];
            else             s = 1.f;
            yr[j] = f2b(myv[jj] * s);
        }
    }
    __syncthreads();

    // ---- GEMM3: H2 = relu(Y2 x fcw1^T) ----
    {
        const short* w3 = wb + 10752;
        #pragma unroll
        for (int nt = 0; nt < 6; ++nt) acc[nt] = (f32x4){0.f, 0.f, 0.f, 0.f};
        #pragma unroll
        for (int k0 = 0; k0 < 96; k0 += 32) {
            bf16x8 a = *(const bf16x8*)(Ya + k0 + quad * 8);
            #pragma unroll
            for (int nt = 0; nt < 6; ++nt) {
                bf16x8 b = *(const bf16x8*)(w3 + (nt * 16 + nloc) * 96 + k0 + quad * 8);
                acc[nt] = __builtin_amdgcn_mfma_f32_16x16x32_bf16(a, b, acc[nt], 0, 0, 0);
            }
        }
        #pragma unroll
        for (int nt = 0; nt < 6; ++nt)
            #pragma unroll
            for (int r = 0; r < 4; ++r)
                Hb[(hrow + r) * YP + nt * 16 + nloc] = f2b(fmaxf(acc[nt][r], 0.f));
    }
    __syncthreads();

    // ---- GEMM4: OUT = H2 x fcw2^T ----
    {
        const short* w4 = wb + 19968;
        f32x4 oacc[3];
        #pragma unroll
        for (int nt = 0; nt < 3; ++nt) oacc[nt] = (f32x4){0.f, 0.f, 0.f, 0.f};
        #pragma unroll
        for (int k0 = 0; k0 < 96; k0 += 32) {
            bf16x8 a = *(const bf16x8*)(Ha + k0 + quad * 8);
            #pragma unroll
            for (int nt = 0; nt < 3; ++nt) {
                bf16x8 b = *(const bf16x8*)(w4 + (nt * 16 + nloc) * 96 + k0 + quad * 8);
                oacc[nt] = __builtin_amdgcn_mfma_f32_16x16x32_bf16(a, b, oacc[nt], 0, 0, 0);
            }
        }
        #pragma unroll
        for (int nt = 0; nt < 3; ++nt) {
            int oc = nt * 16 + nloc;
            if (oc < 40) {
                #pragma unroll
                for (int r = 0; r < 4; ++r)
                    out[(q0 + hrow + r) * 40 + oc] = oacc[nt][r];
            }
        }
    }
}

extern "C" void kernel_launch(void* const* d_in, const int* in_sizes, int n_in,
                              void* d_out, int out_size, void* d_ws, size_t ws_size,
                              hipStream_t stream) {
    const float* vert_xy = (const float*)d_in[0];
    const float* ft1     = (const float*)d_in[1];
    const float* ft_xy   = (const float*)d_in[2];
    const float* vert    = (const float*)d_in[3];
    const float* v       = (const float*)d_in[4];
    const float* vvis    = (const float*)d_in[5];
    const float* qvis    = (const float*)d_in[6];
    const float* ixy     = (const float*)d_in[7];
    const float* img     = (const float*)d_in[8];
    const float* lat     = (const float*)d_in[9];
    const float* fcw1    = (const float*)d_in[10];
    const float* fcw2    = (const float*)d_in[11];
    const float* atw1    = (const float*)d_in[12];
    const float* atw2    = (const float*)d_in[13];
    const float* gtw1    = (const float*)d_in[14];
    const float* gtg1    = (const float*)d_in[15];
    const float* gtb1    = (const float*)d_in[16];
    const float* gtw2    = (const float*)d_in[17];
    const float* gtg2    = (const float*)d_in[18];
    const float* gtb2    = (const float*)d_in[19];
    const float* c3w1    = (const float*)d_in[20];
    const float* c3g1    = (const float*)d_in[21];
    const float* c3b1    = (const float*)d_in[22];
    const float* c3w2    = (const float*)d_in[23];
    const float* c3g2    = (const float*)d_in[24];
    const float* c3b2    = (const float*)d_in[25];
    const float* c4w1    = (const float*)d_in[26];
    const float* c4g1    = (const float*)d_in[27];
    const float* c4b1    = (const float*)d_in[28];
    const float* c4w2    = (const float*)d_in[29];
    const float* c4g2    = (const float*)d_in[30];
    const float* c4b2    = (const float*)d_in[31];
    float* out = (float*)d_out;
    float* ws  = (float*)d_ws;
    float* stats = ws + WS_STATS;
    float* gfc   = ws + WS_GFC;
    float* gth   = ws + WS_GTH;
    float* vfb   = ws + WS_VF;
    float* c3a   = ws + WS_C3A;
    float* c3bb  = ws + WS_C3B;
    float* c4a   = ws + WS_C4A;
    float* c4bb  = ws + WS_C4B;
    float* part_c3 = ws + WS_C4A;            // c4a not live during c3 chain
    short* wbf     = (short*)(ws + WS_C3A);  // c3a dead after c3 conv2 (24576 shorts)
    float* part_c4 = ws + WS_C3B;            // c3bb dead after apool(c3)
    // after apool(c4), c4bb region is dead; carve argmin scratch out of it:
    int*    idx   = (int*)(ws + WS_C4B);                     // 65536 ints
    float*  bestd = ws + WS_C4B + 65536;                     // 8*65536 floats
    int*    besti = (int*)(ws + WS_C4B + 65536 + 524288);    // 8*65536 ints
    float4* vert4 = (float4*)(ws + WS_C4B + 65536 + 1048576); // 1558 float4

    feat_sample_k<<<25, 64, 0, stream>>>(vert_xy, img, ft1, vfb);

    // c3 chain: ft1 (8,64,64) -> (21) -> (42) -> pool(LN fused) -> gfc cols 9..17
    conv4_k<7><<<dim3(4, 3), 256, 0, stream>>>(ft1, c3w1, c3a, part_c3, 8, 64, 64);
    ln_finalize_k<<<1, 64, 0, stream>>>(part_c3, stats + 0, 21, 4, 1.f / 4096.f);
    ln_apply_k<<<21 * 16, 256, 0, stream>>>(c3a, stats + 0, c3g1, c3b1, 4096);
    conv4_k<7><<<dim3(4, 6), 256, 0, stream>>>(c3a, c3w2, c3bb, part_c3, 21, 64, 64);
    wcvt_k<<<96, 256, 0, stream>>>(atw1, atw2, fcw1, fcw2, wbf);  // c3a now dead
    ln_finalize_k<<<1, 64, 0, stream>>>(part_c3, stats + 128, 42, 4, 1.f / 4096.f);
    apool3ln_k<<<42 * 9, 256, 0, stream>>>(c3bb, stats + 128, c3g2, c3b2, gfc, 64, 64, 9);

    // c4 chain: img (3,256,256) -> (21) -> (42) -> pool(LN fused) -> gfc cols 0..8
    conv4_k<7><<<dim3(64, 3), 256, 0, stream>>>(img, c4w1, c4a, part_c4, 3, 256, 256);
    ln_finalize_k<<<1, 64, 0, stream>>>(part_c4, stats + 256, 21, 64, 1.f / 65536.f);
    ln_apply_k<<<21 * 256, 256, 0, stream>>>(c4a, stats + 256, c4g1, c4b1, 65536);
    conv4_k<7><<<dim3(64, 6), 256, 0, stream>>>(c4a, c4w2, c4bb, part_c4, 21, 256, 256);
    ln_finalize_k<<<1, 64, 0, stream>>>(part_c4, stats + 384, 42, 64, 1.f / 65536.f);
    apool3ln_k<<<42 * 9, 256, 0, stream>>>(c4bb, stats + 384, c4g2, c4b2, gfc, 256, 256, 0);

    // argmin AFTER apool(c4): scratch overlaps the now-dead c4bb region
    vprep_k<<<25, 64, 0, stream>>>(vert, vert4);
    argmin_part_k<<<dim3(NQ_ / 256, VSPLIT), 256, 0, stream>>>(v, vert4, bestd, besti);
    argmin_comb_k<<<NQ_ / 256, 256, 0, stream>>>(bestd, besti, idx);

    // global-token conv1d stack -> vf cols 11..28
    gt1_k<<<779, 64, 0, stream>>>(gfc, gtw1, gtg1, gtb1, gth);
    gt2_k<<<1558, 256, 0, stream>>>(gth, gtw2, gtg2, gtb2, vfb);

    // fused per-query MFMA MLP path
    mlp_mfma_k<<<NQ_ / 64, 256, 0, stream>>>(idx, vvis, qvis, ixy, ft_xy, lat, vfb,
                                             wbf, out);
}

// Round 9
// 375.098 us; speedup vs baseline: 1.6874x; 1.0160x over previous
//
#include <hip/hip_runtime.h>
#include <hip/hip_bf16.h>
#include <math.h>

#define NQ_    65536
#define NV_    1558
#define HALF_V 779
#define VSPLIT 8
#define VCHUNK 195   // ceil(1558/8); ranges ascending in p

// ws layout in floats (total 4,452,352 floats = 17.8 MB)
#define WS_STATS 0          //   512
#define WS_GFC   512        //   768
#define WS_GTH   1280       // 14080
#define WS_VF    15360      // 50176 (1558*32)
#define WS_C3A   65536      // 86016  (reused: bf16 weights after c3 conv2)
#define WS_C3B   151552     // 172032 (tail reused for c4 stat partials)
#define WS_C4A   323584     // 1376256 (head reused for c3 stat partials)
#define WS_C4B   1699840    // 2752512 (reused after apool(c4): idx/bestd/besti/vert4)

typedef __attribute__((ext_vector_type(8))) short bf16x8;
typedef __attribute__((ext_vector_type(4))) float f32x4;

__device__ __forceinline__ short f2b(float x) {
    union { __hip_bfloat16 h; short s; } u; u.h = __float2bfloat16(x); return u.s;
}

// ---------------- bilinear feature sampling (vertices) ----------------
__device__ __forceinline__ void bsample(const float* __restrict__ f, int C, int H, int W,
                                        float xn, float yn, float* __restrict__ o) {
    float x = (xn + 1.f) * 0.5f * (float)(W - 1);
    float y = (yn + 1.f) * 0.5f * (float)(H - 1);
    float x0f = floorf(x), y0f = floorf(y);
    float wx = x - x0f, wy = y - y0f;
    int x0 = (int)fminf(fmaxf(x0f, 0.f), (float)(W - 1));
    int x1 = (int)fminf(fmaxf(x0f + 1.f, 0.f), (float)(W - 1));
    int y0 = (int)fminf(fmaxf(y0f, 0.f), (float)(H - 1));
    int y1 = (int)fminf(fmaxf(y0f + 1.f, 0.f), (float)(H - 1));
    for (int c = 0; c < C; ++c) {
        const float* b = f + c * H * W;
        float v00 = b[y0 * W + x0], v01 = b[y0 * W + x1];
        float v10 = b[y1 * W + x0], v11 = b[y1 * W + x1];
        o[c] = v00 * (1.f - wx) * (1.f - wy) + v01 * wx * (1.f - wy)
             + v10 * (1.f - wx) * wy       + v11 * wx * wy;
    }
}

__global__ void feat_sample_k(const float* __restrict__ vert_xy,
                              const float* __restrict__ img,
                              const float* __restrict__ ft1,
                              float* __restrict__ vf) {
    int v = blockIdx.x * 64 + threadIdx.x;
    if (v >= NV_) return;
    float xn = vert_xy[v * 2 + 0], yn = vert_xy[v * 2 + 1];
    float tmp[8];
    bsample(img, 3, 256, 256, xn, yn, tmp);
    float* o = vf + v * 32;
    o[0] = tmp[0]; o[1] = tmp[1]; o[2] = tmp[2];
    bsample(ft1, 8, 64, 64, xn, yn, tmp);
    #pragma unroll
    for (int c = 0; c < 8; ++c) o[3 + c] = tmp[c];
}

// ---------------- conv2d 3x3 pad1: 4 pixels x CB channels per thread,
// ---------------- aligned float4 row loads, fused per-(channel,block) stats ----------------
// CB=3 keeps VGPR ~40 and grid large (TLP >> ILP was the round-8 lesson).
template <int CB>
__global__ __launch_bounds__(256) void conv4_k(
    const float* __restrict__ in, const float* __restrict__ w,
    float* __restrict__ out, float* __restrict__ part,
    int Cin, int H, int W) {
    int c0 = blockIdx.y * CB;
    int tid = threadIdx.x;
    int px0 = (blockIdx.x * 256 + tid) * 4;
    int HW = H * W;
    int y = px0 / W, x = px0 % W;      // x is a multiple of 4
    float acc[CB][4];
    #pragma unroll
    for (int j = 0; j < CB; ++j)
        #pragma unroll
        for (int p = 0; p < 4; ++p) acc[j][p] = 0.f;
    const float* wbase = w + c0 * Cin * 9;
    #pragma unroll 2
    for (int ci = 0; ci < Cin; ++ci) {
        const float* ip = in + ci * HW;
        float win[3][6];
        #pragma unroll
        for (int r = 0; r < 3; ++r) {
            int yy = y + r - 1;
            bool okY = (yy >= 0) && (yy < H);
            const float* rp = ip + yy * W;
            if (okY) {
                float4 m4 = *(const float4*)(rp + x);   // 16B-aligned
                win[r][1] = m4.x; win[r][2] = m4.y; win[r][3] = m4.z; win[r][4] = m4.w;
                win[r][0] = (x > 0)     ? rp[x - 1] : 0.f;
                win[r][5] = (x + 4 < W) ? rp[x + 4] : 0.f;
            } else {
                #pragma unroll
                for (int k = 0; k < 6; ++k) win[r][k] = 0.f;
            }
        }
        const float* wc = wbase + ci * 9;
        #pragma unroll
        for (int j = 0; j < CB; ++j) {
            const float* wj = wc + j * Cin * 9;   // wave-uniform -> scalar loads
            #pragma unroll
            for (int r = 0; r < 3; ++r) {
                float w0 = wj[r * 3 + 0], w1 = wj[r * 3 + 1], w2 = wj[r * 3 + 2];
                #pragma unroll
                for (int p = 0; p < 4; ++p)
                    acc[j][p] = fmaf(w0, win[r][p],
                                fmaf(w1, win[r][p + 1],
                                fmaf(w2, win[r][p + 2], acc[j][p])));
            }
        }
    }
    #pragma unroll
    for (int j = 0; j < CB; ++j) {
        float4 o4 = make_float4(acc[j][0], acc[j][1], acc[j][2], acc[j][3]);
        *(float4*)(out + (c0 + j) * HW + px0) = o4;
    }

    // fused stats: per-(channel, block) sum / sumsq
    __shared__ float sred[4][CB][2];
    int lane = tid & 63, wave = tid >> 6;
    #pragma unroll
    for (int j = 0; j < CB; ++j) {
        float s  = acc[j][0] + acc[j][1] + acc[j][2] + acc[j][3];
        float qq = acc[j][0] * acc[j][0] + acc[j][1] * acc[j][1]
                 + acc[j][2] * acc[j][2] + acc[j][3] * acc[j][3];
        #pragma unroll
        for (int off = 1; off < 64; off <<= 1) {
            s  += __shfl_xor(s, off, 64);
            qq += __shfl_xor(qq, off, 64);
        }
        if (lane == 0) { sred[wave][j][0] = s; sred[wave][j][1] = qq; }
    }
    __syncthreads();
    if (tid < CB) {
        float s  = sred[0][tid][0] + sred[1][tid][0] + sred[2][tid][0] + sred[3][tid][0];
        float qq = sred[0][tid][1] + sred[1][tid][1] + sred[2][tid][1] + sred[3][tid][1];
        int c = c0 + tid;
        part[(c * gridDim.x + blockIdx.x) * 2 + 0] = s;
        part[(c * gridDim.x + blockIdx.x) * 2 + 1] = qq;
    }
}

// ---------------- reduce per-block partials -> per-channel (mean, rsqrt(var)) ----------------
__global__ void ln_finalize_k(const float* __restrict__ part, float* __restrict__ stats,
                              int C, int nb, float invHW) {
    int c = threadIdx.x;
    if (c >= C) return;
    float s = 0.f, s2 = 0.f;
    for (int i = 0; i < nb; ++i) {
        s  += part[(c * nb + i) * 2 + 0];
        s2 += part[(c * nb + i) * 2 + 1];
    }
    float m = s * invHW;
    float var = s2 * invHW - m * m;
    if (var < 0.f) var = 0.f;
    stats[c * 2 + 0] = m;
    stats[c * 2 + 1] = rsqrtf(var + 1e-6f);
}

// ---------------- LN apply (+relu): 2 stat loads per thread (feeds next conv) ----------------
__global__ __launch_bounds__(256) void ln_apply_k(
    float* __restrict__ buf, const float* __restrict__ stats,
    const float* __restrict__ g, const float* __restrict__ b, int HW) {
    int i = blockIdx.x * 256 + threadIdx.x;
    int c = i / HW;      // HW is a power of two
    int hw = i % HW;
    float m = stats[c * 2], inv = stats[c * 2 + 1];
    float x = buf[i];
    float r = fmaf((x - m) * inv, g[hw], b[hw]);
    buf[i] = fmaxf(r, 0.f);
}

// ---------------- adaptive 3x3 avg pool of relu(LN(x)), no materialization ----------------
__global__ __launch_bounds__(256) void apool3ln_k(
    const float* __restrict__ in, const float* __restrict__ stats,
    const float* __restrict__ g, const float* __restrict__ b,
    float* __restrict__ gfc, int H, int W, int colOff) {
    int c = (int)blockIdx.x / 9;
    int bin = (int)blockIdx.x % 9;
    int bh = bin / 3, bw = bin % 3;
    int hs = bh * H / 3, he = ((bh + 1) * H + 2) / 3;
    int wsx = bw * W / 3, we = ((bw + 1) * W + 2) / 3;
    int rw = we - wsx, rh = he - hs, n = rw * rh;
    const float* bb = in + c * H * W;
    float m = stats[c * 2], inv = stats[c * 2 + 1];   // c uniform per block -> scalar
    float s = 0.f;
    for (int t = threadIdx.x; t < n; t += 256) {
        int iy = t / rw, ix = t % rw;
        int hw = (hs + iy) * W + (wsx + ix);
        float x = bb[hw];
        float r = fmaf((x - m) * inv, g[hw], b[hw]);  // bit-identical to ln_apply->apool
        s += fmaxf(r, 0.f);
    }
    __shared__ float rs[256];
    rs[threadIdx.x] = s;
    __syncthreads();
    for (int st = 128; st > 0; st >>= 1) {
        if (threadIdx.x < st) rs[threadIdx.x] += rs[threadIdx.x + st];
        __syncthreads();
    }
    if (threadIdx.x == 0) gfc[c * 18 + colOff + bin] = rs[0] / (float)n;
}

// ---------------- conv1d (42->779) + LN(18) + relu ----------------
__global__ __launch_bounds__(64) void gt1_k(const float* __restrict__ gfc,
                                            const float* __restrict__ w,
                                            const float* __restrict__ g,
                                            const float* __restrict__ b,
                                            float* __restrict__ outh) {
    int o = blockIdx.x;     // 779
    int p = threadIdx.x;
    __shared__ float vals[18];
    if (p < 18) {
        float acc = 0.f;
        const float* wo = w + o * 42 * 3;
        for (int c = 0; c < 42; ++c) {
            const float* gr = gfc + c * 18;
            #pragma unroll
            for (int k = 0; k < 3; ++k) {
                int pk = p + k - 1;
                if (pk >= 0 && pk < 18) acc = fmaf(wo[c * 3 + k], gr[pk], acc);
            }
        }
        vals[p] = acc;
    }
    __syncthreads();
    if (p < 18) {
        float s = 0.f, s2 = 0.f;
        #pragma unroll
        for (int j = 0; j < 18; ++j) { float x = vals[j]; s += x; s2 += x * x; }
        float m = s / 18.f;
        float var = s2 / 18.f - m * m;
        if (var < 0.f) var = 0.f;
        float inv = rsqrtf(var + 1e-6f);
        float r = fmaf((vals[p] - m) * inv, g[p], b[p]);
        outh[o * 18 + p] = fmaxf(r, 0.f);
    }
}

// ---------------- conv1d (779->1558) + LN(18) + relu -> vf cols 11..28 ----------------
// 4 waves per block; each wave covers a contiguous quarter of the 779 channels.
__global__ __launch_bounds__(256) void gt2_k(const float* __restrict__ h,
                                             const float* __restrict__ w,
                                             const float* __restrict__ g,
                                             const float* __restrict__ b,
                                             float* __restrict__ vf) {
    int o = blockIdx.x;     // 1558
    int t = threadIdx.x, lane = t & 63, wave = t >> 6;
    __shared__ float red[4][18];
    float part[18];
    #pragma unroll
    for (int p = 0; p < 18; ++p) part[p] = 0.f;
    int c0 = wave * 195;
    int c1 = c0 + 195; if (c1 > HALF_V) c1 = HALF_V;
    for (int c = c0 + lane; c < c1; c += 64) {
        const float* wr = w + (o * HALF_V + c) * 3;
        float w0 = wr[0], w1 = wr[1], w2 = wr[2];
        const float* hr = h + c * 18;
        float hv[18];
        #pragma unroll
        for (int p = 0; p < 18; ++p) hv[p] = hr[p];
        #pragma unroll
        for (int p = 0; p < 18; ++p) {
            float a = w1 * hv[p];
            if (p > 0)  a = fmaf(w0, hv[p - 1], a);
            if (p < 17) a = fmaf(w2, hv[p + 1], a);
            part[p] += a;
        }
    }
    #pragma unroll
    for (int p = 0; p < 18; ++p) {
        float vv = part[p];
        #pragma unroll
        for (int off = 32; off > 0; off >>= 1) vv += __shfl_xor(vv, off, 64);
        part[p] = vv;
    }
    if (lane == 0) {
        #pragma unroll
        for (int p = 0; p < 18; ++p) red[wave][p] = part[p];
    }
    __syncthreads();
    if (t < 18) {
        float s = red[0][t] + red[1][t] + red[2][t] + red[3][t];
        red[0][t] = s;
    }
    __syncthreads();
    if (t < 18) {
        float s = 0.f, s2 = 0.f;
        #pragma unroll
        for (int j = 0; j < 18; ++j) { float x = red[0][j]; s += x; s2 += x * x; }
        float m = s / 18.f;
        float var = s2 / 18.f - m * m;
        if (var < 0.f) var = 0.f;
        float inv = rsqrtf(var + 1e-6f);
        float r = fmaf((red[0][t] - m) * inv, g[t], b[t]);
        vf[o * 32 + 11 + t] = fmaxf(r, 0.f);
    }
}

// ---------------- argmin: one THREAD per query, wave-uniform vertex scan ----------------
__global__ void vprep_k(const float* __restrict__ vert, float4* __restrict__ v4) {
    int i = blockIdx.x * 64 + threadIdx.x;
    if (i >= NV_) return;
    float x = vert[i * 3 + 0], y = vert[i * 3 + 1], z = vert[i * 3 + 2];
    float pn = __fadd_rn(__fadd_rn(__fmul_rn(x, x), __fmul_rn(y, y)), __fmul_rn(z, z));
    v4[i] = make_float4(x, y, z, pn);
}

__global__ __launch_bounds__(256) void argmin_part_k(
    const float* __restrict__ v, const float4* __restrict__ v4,
    float* __restrict__ bestd, int* __restrict__ besti) {
    int q = blockIdx.x * 256 + threadIdx.x;
    int r = blockIdx.y;
    int p0 = r * VCHUNK;
    int p1 = p0 + VCHUNK; if (p1 > NV_) p1 = NV_;
    float vx = v[q * 3 + 0], vy = v[q * 3 + 1], vz = v[q * 3 + 2];
    float vn = __fadd_rn(__fadd_rn(__fmul_rn(vx, vx), __fmul_rn(vy, vy)), __fmul_rn(vz, vz));
    float best = 3.4e38f;
    int bi = p0;
    // d2 = (|v|^2 + |p|^2) - 2*(v.p); np rounding preserved (no fma contraction).
    // v4[p] is wave-uniform -> scalar K$ loads; strict < keeps smallest p on ties.
    #pragma unroll 4
    for (int p = p0; p < p1; ++p) {
        float4 pv = v4[p];
        float dot = __fadd_rn(__fadd_rn(__fmul_rn(vx, pv.x), __fmul_rn(vy, pv.y)), __fmul_rn(vz, pv.z));
        float d2 = __fsub_rn(__fadd_rn(vn, pv.w), __fmul_rn(2.f, dot));
        if (d2 < best) { best = d2; bi = p; }
    }
    bestd[r * NQ_ + q] = best;
    besti[r * NQ_ + q] = bi;
}

__global__ __launch_bounds__(256) void argmin_comb_k(
    const float* __restrict__ bestd, const int* __restrict__ besti,
    int* __restrict__ idx) {
    int q = blockIdx.x * 256 + threadIdx.x;
    float best = bestd[q];
    int bi = besti[q];
    #pragma unroll
    for (int r = 1; r < VSPLIT; ++r) {
        float d = bestd[r * NQ_ + q];
        int i2 = besti[r * NQ_ + q];
        if (d < best) { best = d; bi = i2; }   // ranges ascend in p; strict < keeps first min
    }
    idx[q] = bi;
}

// ---------------- weight f32 -> bf16 (with row zero-padding) ----------------
// wb layout (shorts): [0,9216) atw1 ; [9216,10752) atw2 pad to 16 rows ;
//                     [10752,19968) fcw1 ; [19968,24576) fcw2 pad to 48 rows
__global__ void wcvt_k(const float* __restrict__ atw1, const float* __restrict__ atw2,
                       const float* __restrict__ fcw1, const float* __restrict__ fcw2,
                       short* __restrict__ wb) {
    int i = blockIdx.x * 256 + threadIdx.x;   // grid 96 -> 24576
    short v = 0;
    if (i < 9216) v = f2b(atw1[i]);
    else if (i < 10752) { int j = i - 9216; v = (j < 576) ? f2b(atw2[j]) : (short)0; }
    else if (i < 19968) v = f2b(fcw1[i - 10752]);
    else { int j = i - 19968; v = (j < 3840) ? f2b(fcw2[j]) : (short)0; }
    wb[i] = v;
}

// ---------------- MFMA MLP: 16 queries per wave, 64 per block ----------------
#define YP 104   // padded LDS row stride in shorts (2-way bank aliasing only)

__global__ __launch_bounds__(256) void mlp_mfma_k(
    const int* __restrict__ idx,
    const float* __restrict__ vvis, const float* __restrict__ qvis,
    const float* __restrict__ ixy, const float* __restrict__ fxy,
    const float* __restrict__ lat, const float* __restrict__ vf,
    const short* __restrict__ wb, float* __restrict__ out) {
    __shared__ short Y[64 * YP];
    __shared__ short Hb[64 * YP];
    __shared__ float A6[64 * 8];
    int t = threadIdx.x;
    int lane = t & 63, wave = t >> 6;
    int q0 = blockIdx.x * 64;

    // ---- y build: 4 lanes per query, bf16 into LDS; keep f32 copy in regs ----
    int ql = t >> 2, part = t & 3;
    int q = q0 + ql;
    int bi = idx[q];
    int bi2 = bi + HALF_V; if (bi2 >= NV_) bi2 -= NV_;
    const float* f  = vf + bi * 32;
    const float* ft = vf + bi2 * 32;
    float vis = vvis[bi], vist = vvis[bi2];
    short* yr = &Y[ql * YP];
    float myv[24];
    #pragma unroll
    for (int jj = 0; jj < 24; ++jj) {
        int j = part * 24 + jj;
        float val;
        if (j < 3)       val = ixy[q * 3 + j];
        else if (j < 11) val = fxy[q * 8 + j - 3];
        else if (j < 22) val = f[j - 11] * vis;
        else if (j < 33) val = ft[j - 22] * vist;
        else if (j < 51) val = f[11 + j - 33] * vis;
        else if (j < 69) val = ft[11 + j - 51] * vist;
        else if (j < 93) val = lat[q * 24 + j - 69];
        else if (j == 93) val = qvis[q];
        else if (j == 94) val = vis;
        else              val = vist;
        myv[jj] = val;
        yr[j] = f2b(val);
    }
    __syncthreads();

    int nloc = lane & 15, quad = lane >> 4;
    const short* Ya = &Y[(wave * 16 + nloc) * YP];
    const short* Ha = &Hb[(wave * 16 + nloc) * YP];
    int hrow = wave * 16 + quad * 4;    // C-layout row base for this lane

    // ---- GEMM1: H = relu(Y x atw1^T) ----
    f32x4 acc[6];
    #pragma unroll
    for (int nt = 0; nt < 6; ++nt) acc[nt] = (f32x4){0.f, 0.f, 0.f, 0.f};
    #pragma unroll
    for (int k0 = 0; k0 < 96; k0 += 32) {
        bf16x8 a = *(const bf16x8*)(Ya + k0 + quad * 8);
        #pragma unroll
        for (int nt = 0; nt < 6; ++nt) {
            bf16x8 b = *(const bf16x8*)(wb + (nt * 16 + nloc) * 96 + k0 + quad * 8);
            acc[nt] = __builtin_amdgcn_mfma_f32_16x16x32_bf16(a, b, acc[nt], 0, 0, 0);
        }
    }
    #pragma unroll
    for (int nt = 0; nt < 6; ++nt)
        #pragma unroll
        for (int r = 0; r < 4; ++r)
            Hb[(hrow + r) * YP + nt * 16 + nloc] = f2b(fmaxf(acc[nt][r], 0.f));
    __syncthreads();

    // ---- GEMM2: at6 = sigmoid(H x atw2^T) ----
    {
        const short* w2 = wb + 9216;
        f32x4 a2 = (f32x4){0.f, 0.f, 0.f, 0.f};
        #pragma unroll
        for (int k0 = 0; k0 < 96; k0 += 32) {
            bf16x8 a = *(const bf16x8*)(Ha + k0 + quad * 8);
            bf16x8 b = *(const bf16x8*)(w2 + nloc * 96 + k0 + quad * 8);
            a2 = __builtin_amdgcn_mfma_f32_16x16x32_bf16(a, b, a2, 0, 0, 0);
        }
        if (nloc < 6) {
            #pragma unroll
            for (int r = 0; r < 4; ++r)
                A6[(hrow + r) * 8 + nloc] = 1.f / (1.f + expf(-a2[r]));
        }
    }
    __syncthreads();

    // ---- scale Y in place from f32 register copy ----
    {
        const float* ap = &A6[ql * 8];
        #pragma unroll
        for (int jj = 0; jj < 24; ++jj) {
            int j = part * 24 + jj;
            float s;
            if (j < 11)      s = ap[0];
            else if (j < 22) s = ap[1];
            else if (j < 33) s = ap[2];
            else if (j < 51) s = ap[3];
            else if (j < 69) s = ap[4];
            else if (j < 93) s = ap[5];
            else             s = 1.f;
            yr[j] = f2b(myv[jj] * s);
        }
    }
    __syncthreads();

    // ---- GEMM3: H2 = relu(Y2 x fcw1^T) ----
    {
        const short* w3 = wb + 10752;
        #pragma unroll
        for (int nt = 0; nt < 6; ++nt) acc[nt] = (f32x4){0.f, 0.f, 0.f, 0.f};
        #pragma unroll
        for (int k0 = 0; k0 < 96; k0 += 32) {
            bf16x8 a = *(const bf16x8*)(Ya + k0 + quad * 8);
            #pragma unroll
            for (int nt = 0; nt < 6; ++nt) {
                bf16x8 b = *(const bf16x8*)(w3 + (nt * 16 + nloc) * 96 + k0 + quad * 8);
                acc[nt] = __builtin_amdgcn_mfma_f32_16x16x32_bf16(a, b, acc[nt], 0, 0, 0);
            }
        }
        #pragma unroll
        for (int nt = 0; nt < 6; ++nt)
            #pragma unroll
            for (int r = 0; r < 4; ++r)
                Hb[(hrow + r) * YP + nt * 16 + nloc] = f2b(fmaxf(acc[nt][r], 0.f));
    }
    __syncthreads();

    // ---- GEMM4: OUT = H2 x fcw2^T ----
    {
        const short* w4 = wb + 19968;
        f32x4 oacc[3];
        #pragma unroll
        for (int nt = 0; nt < 3; ++nt) oacc[nt] = (f32x4){0.f, 0.f, 0.f, 0.f};
        #pragma unroll
        for (int k0 = 0; k0 < 96; k0 += 32) {
            bf16x8 a = *(const bf16x8*)(Ha + k0 + quad * 8);
            #pragma unroll
            for (int nt = 0; nt < 3; ++nt) {
                bf16x8 b = *(const bf16x8*)(w4 + (nt * 16 + nloc) * 96 + k0 + quad * 8);
                oacc[nt] = __builtin_amdgcn_mfma_f32_16x16x32_bf16(a, b, oacc[nt], 0, 0, 0);
            }
        }
        #pragma unroll
        for (int nt = 0; nt < 3; ++nt) {
            int oc = nt * 16 + nloc;
            if (oc < 40) {
                #pragma unroll
                for (int r = 0; r < 4; ++r)
                    out[(q0 + hrow + r) * 40 + oc] = oacc[nt][r];
            }
        }
    }
}

extern "C" void kernel_launch(void* const* d_in, const int* in_sizes, int n_in,
                              void* d_out, int out_size, void* d_ws, size_t ws_size,
                              hipStream_t stream) {
    const float* vert_xy = (const float*)d_in[0];
    const float* ft1     = (const float*)d_in[1];
    const float* ft_xy   = (const float*)d_in[2];
    const float* vert    = (const float*)d_in[3];
    const float* v       = (const float*)d_in[4];
    const float* vvis    = (const float*)d_in[5];
    const float* qvis    = (const float*)d_in[6];
    const float* ixy     = (const float*)d_in[7];
    const float* img     = (const float*)d_in[8];
    const float* lat     = (const float*)d_in[9];
    const float* fcw1    = (const float*)d_in[10];
    const float* fcw2    = (const float*)d_in[11];
    const float* atw1    = (const float*)d_in[12];
    const float* atw2    = (const float*)d_in[13];
    const float* gtw1    = (const float*)d_in[14];
    const float* gtg1    = (const float*)d_in[15];
    const float* gtb1    = (const float*)d_in[16];
    const float* gtw2    = (const float*)d_in[17];
    const float* gtg2    = (const float*)d_in[18];
    const float* gtb2    = (const float*)d_in[19];
    const float* c3w1    = (const float*)d_in[20];
    const float* c3g1    = (const float*)d_in[21];
    const float* c3b1    = (const float*)d_in[22];
    const float* c3w2    = (const float*)d_in[23];
    const float* c3g2    = (const float*)d_in[24];
    const float* c3b2    = (const float*)d_in[25];
    const float* c4w1    = (const float*)d_in[26];
    const float* c4g1    = (const float*)d_in[27];
    const float* c4b1    = (const float*)d_in[28];
    const float* c4w2    = (const float*)d_in[29];
    const float* c4g2    = (const float*)d_in[30];
    const float* c4b2    = (const float*)d_in[31];
    float* out = (float*)d_out;
    float* ws  = (float*)d_ws;
    float* stats = ws + WS_STATS;
    float* gfc   = ws + WS_GFC;
    float* gth   = ws + WS_GTH;
    float* vfb   = ws + WS_VF;
    float* c3a   = ws + WS_C3A;
    float* c3bb  = ws + WS_C3B;
    float* c4a   = ws + WS_C4A;
    float* c4bb  = ws + WS_C4B;
    float* part_c3 = ws + WS_C4A;            // c4a not live during c3 chain
    short* wbf     = (short*)(ws + WS_C3A);  // c3a dead after c3 conv2 (24576 shorts)
    float* part_c4 = ws + WS_C3B;            // c3bb dead after apool(c3)
    // after apool(c4), c4bb region is dead; carve argmin scratch out of it:
    int*    idx   = (int*)(ws + WS_C4B);                     // 65536 ints
    float*  bestd = ws + WS_C4B + 65536;                     // 8*65536 floats
    int*    besti = (int*)(ws + WS_C4B + 65536 + 524288);    // 8*65536 ints
    float4* vert4 = (float4*)(ws + WS_C4B + 65536 + 1048576); // 1558 float4

    feat_sample_k<<<25, 64, 0, stream>>>(vert_xy, img, ft1, vfb);

    // c3 chain: ft1 (8,64,64) -> (21) -> (42) -> pool(LN fused) -> gfc cols 9..17
    conv4_k<3><<<dim3(4, 7), 256, 0, stream>>>(ft1, c3w1, c3a, part_c3, 8, 64, 64);
    ln_finalize_k<<<1, 64, 0, stream>>>(part_c3, stats + 0, 21, 4, 1.f / 4096.f);
    ln_apply_k<<<21 * 16, 256, 0, stream>>>(c3a, stats + 0, c3g1, c3b1, 4096);
    conv4_k<3><<<dim3(4, 14), 256, 0, stream>>>(c3a, c3w2, c3bb, part_c3, 21, 64, 64);
    wcvt_k<<<96, 256, 0, stream>>>(atw1, atw2, fcw1, fcw2, wbf);  // c3a now dead
    ln_finalize_k<<<1, 64, 0, stream>>>(part_c3, stats + 128, 42, 4, 1.f / 4096.f);
    apool3ln_k<<<42 * 9, 256, 0, stream>>>(c3bb, stats + 128, c3g2, c3b2, gfc, 64, 64, 9);

    // c4 chain: img (3,256,256) -> (21) -> (42) -> pool(LN fused) -> gfc cols 0..8
    conv4_k<3><<<dim3(64, 7), 256, 0, stream>>>(img, c4w1, c4a, part_c4, 3, 256, 256);
    ln_finalize_k<<<1, 64, 0, stream>>>(part_c4, stats + 256, 21, 64, 1.f / 65536.f);
    ln_apply_k<<<21 * 256, 256, 0, stream>>>(c4a, stats + 256, c4g1, c4b1, 65536);
    conv4_k<3><<<dim3(64, 14), 256, 0, stream>>>(c4a, c4w2, c4bb, part_c4, 21, 256, 256);
    ln_finalize_k<<<1, 64, 0, stream>>>(part_c4, stats + 384, 42, 64, 1.f / 65536.f);
    apool3ln_k<<<42 * 9, 256, 0, stream>>>(c4bb, stats + 384, c4g2, c4b2, gfc, 256, 256, 0);

    // argmin AFTER apool(c4): scratch overlaps the now-dead c4bb region
    vprep_k<<<25, 64, 0, stream>>>(vert, vert4);
    argmin_part_k<<<dim3(NQ_ / 256, VSPLIT), 256, 0, stream>>>(v, vert4, bestd, besti);
    argmin_comb_k<<<NQ_ / 256, 256, 0, stream>>>(bestd, besti, idx);

    // global-token conv1d stack -> vf cols 11..28
    gt1_k<<<779, 64, 0, stream>>>(gfc, gtw1, gtg1, gtb1, gth);
    gt2_k<<<1558, 256, 0, stream>>>(gth, gtw2, gtg2, gtb2, vfb);

    // fused per-query MFMA MLP path
    mlp_mfma_k<<<NQ_ / 64, 256, 0, stream>>>(idx, vvis, qvis, ixy, ft_xy, lat, vfb,
                                             wbf, out);
}

// Round 10
// 358.595 us; speedup vs baseline: 1.7650x; 1.0460x over previous
//
#include <hip/hip_runtime.h>
#include <hip/hip_bf16.h>
#include <math.h>

#define NQ_    65536
#define NV_    1558
#define HALF_V 779
#define VSPLIT 8
#define VCHUNK 195   // ceil(1558/8); ranges ascending in p

// ws layout in floats (total 4,452,352 floats = 17.8 MB)
#define WS_STATS 0          //   512
#define WS_GFC   512        //   768
#define WS_GTH   1280       // 14080
#define WS_VF    15360      // 50176 (1558*32)
#define WS_C3A   65536      // 86016  (reused: bf16 weights after c3 conv2)
#define WS_C3B   151552     // 172032 (tail reused for c4 stat partials)
#define WS_C4A   323584     // 1376256 (head reused for c3 stat partials)
#define WS_C4B   1699840    // 2752512 (reused after apool(c4): idx/bestd/besti/vert4)

typedef __attribute__((ext_vector_type(8))) short bf16x8;
typedef __attribute__((ext_vector_type(4))) float f32x4;

__device__ __forceinline__ short f2b(float x) {
    union { __hip_bfloat16 h; short s; } u; u.h = __float2bfloat16(x); return u.s;
}

// ---------------- bilinear feature sampling (vertices) ----------------
__device__ __forceinline__ void bsample(const float* __restrict__ f, int C, int H, int W,
                                        float xn, float yn, float* __restrict__ o) {
    float x = (xn + 1.f) * 0.5f * (float)(W - 1);
    float y = (yn + 1.f) * 0.5f * (float)(H - 1);
    float x0f = floorf(x), y0f = floorf(y);
    float wx = x - x0f, wy = y - y0f;
    int x0 = (int)fminf(fmaxf(x0f, 0.f), (float)(W - 1));
    int x1 = (int)fminf(fmaxf(x0f + 1.f, 0.f), (float)(W - 1));
    int y0 = (int)fminf(fmaxf(y0f, 0.f), (float)(H - 1));
    int y1 = (int)fminf(fmaxf(y0f + 1.f, 0.f), (float)(H - 1));
    for (int c = 0; c < C; ++c) {
        const float* b = f + c * H * W;
        float v00 = b[y0 * W + x0], v01 = b[y0 * W + x1];
        float v10 = b[y1 * W + x0], v11 = b[y1 * W + x1];
        o[c] = v00 * (1.f - wx) * (1.f - wy) + v01 * wx * (1.f - wy)
             + v10 * (1.f - wx) * wy       + v11 * wx * wy;
    }
}

__global__ void feat_sample_k(const float* __restrict__ vert_xy,
                              const float* __restrict__ img,
                              const float* __restrict__ ft1,
                              float* __restrict__ vf) {
    int v = blockIdx.x * 64 + threadIdx.x;
    if (v >= NV_) return;
    float xn = vert_xy[v * 2 + 0], yn = vert_xy[v * 2 + 1];
    float tmp[8];
    bsample(img, 3, 256, 256, xn, yn, tmp);
    float* o = vf + v * 32;
    o[0] = tmp[0]; o[1] = tmp[1]; o[2] = tmp[2];
    bsample(ft1, 8, 64, 64, xn, yn, tmp);
    #pragma unroll
    for (int c = 0; c < 8; ++c) o[3 + c] = tmp[c];
}

// ---------------- conv2d 3x3 pad1, LDS-tile staged ----------------
// Block = 256 threads x 4 px = 1024 contiguous pixels (whole rows).
// Per input channel: tile (1024 + 2W floats) staged via coalesced float4 loads,
// double-buffered in LDS; staging regs loaded right after the barrier so global
// latency hides under the 252-FMA compute of the current channel.
// Window reads: 3 aligned ds_read_b128 per row (stride-4-lane, conflict-free).
template <int CB>
__global__ __launch_bounds__(256) void conv_lds_k(
    const float* __restrict__ in, const float* __restrict__ w,
    float* __restrict__ out, float* __restrict__ part,
    int Cin, int H, int W) {
    __shared__ float tile[2][8 + 1536 + 8];   // max tileF = 1024+2*256; +-8 pads
    int tid = threadIdx.x;
    int c0 = blockIdx.y * CB;
    int gpx0 = blockIdx.x * 1024;
    int y0 = gpx0 / W;
    int tileF = 1024 + 2 * W;
    int nf4 = tileF >> 2;
    int HW = H * W;
    int px0 = tid * 4;
    int ty = px0 / W, x = px0 % W;            // x multiple of 4

    float acc[CB][4];
    #pragma unroll
    for (int j = 0; j < CB; ++j)
        #pragma unroll
        for (int p = 0; p < 4; ++p) acc[j][p] = 0.f;

    const float* wbase = w + c0 * Cin * 9;
    float4 sreg[2];

    // prime stage for ci = 0
    #pragma unroll
    for (int k = 0; k < 2; ++k) {
        int idx = tid + k * 256;
        float4 v = make_float4(0.f, 0.f, 0.f, 0.f);
        if (idx < nf4) {
            int gw = idx * 4;
            int gy = y0 - 1 + gw / W, gx = gw % W;
            if (gy >= 0 && gy < H) v = *(const float4*)(in + gy * W + gx);
        }
        sreg[k] = v;
    }
    // stage ci=0 into buf 0
    #pragma unroll
    for (int k = 0; k < 2; ++k) {
        int idx = tid + k * 256;
        if (idx < nf4) *(float4*)(&tile[0][8] + idx * 4) = sreg[k];
    }
    __syncthreads();

    for (int ci = 0; ci < Cin; ++ci) {
        // issue next channel's global loads (consumed after this ci's compute)
        if (ci + 1 < Cin) {
            const float* ipn = in + (ci + 1) * HW;
            #pragma unroll
            for (int k = 0; k < 2; ++k) {
                int idx = tid + k * 256;
                float4 v = make_float4(0.f, 0.f, 0.f, 0.f);
                if (idx < nf4) {
                    int gw = idx * 4;
                    int gy = y0 - 1 + gw / W, gx = gw % W;
                    if (gy >= 0 && gy < H) v = *(const float4*)(ipn + gy * W + gx);
                }
                sreg[k] = v;
            }
        }
        // compute from buf[ci&1]
        {
            const float* tl = &tile[ci & 1][8];
            float win[3][6];
            #pragma unroll
            for (int r = 0; r < 3; ++r) {
                const float* lrow = tl + (ty + r) * W + x;
                float4 B = *(const float4*)(lrow);
                float4 A = *(const float4*)(lrow - 4);   // pad covers x==0
                float4 C = *(const float4*)(lrow + 4);   // pad covers tile end
                win[r][0] = (x > 0) ? A.w : 0.f;
                win[r][1] = B.x; win[r][2] = B.y; win[r][3] = B.z; win[r][4] = B.w;
                win[r][5] = (x + 4 < W) ? C.x : 0.f;
            }
            const float* wc = wbase + ci * 9;
            #pragma unroll
            for (int j = 0; j < CB; ++j) {
                const float* wj = wc + j * Cin * 9;   // wave-uniform -> scalar loads
                #pragma unroll
                for (int r = 0; r < 3; ++r) {
                    float w0 = wj[r * 3 + 0], w1 = wj[r * 3 + 1], w2 = wj[r * 3 + 2];
                    #pragma unroll
                    for (int p = 0; p < 4; ++p)
                        acc[j][p] = fmaf(w0, win[r][p],
                                    fmaf(w1, win[r][p + 1],
                                    fmaf(w2, win[r][p + 2], acc[j][p])));
                }
            }
        }
        // stage next channel into the other buffer (its last readers finished
        // before the barrier at the end of the previous iteration)
        if (ci + 1 < Cin) {
            float* tn = &tile[(ci + 1) & 1][8];
            #pragma unroll
            for (int k = 0; k < 2; ++k) {
                int idx = tid + k * 256;
                if (idx < nf4) *(float4*)(tn + idx * 4) = sreg[k];
            }
        }
        __syncthreads();
    }

    #pragma unroll
    for (int j = 0; j < CB; ++j) {
        float4 o4 = make_float4(acc[j][0], acc[j][1], acc[j][2], acc[j][3]);
        *(float4*)(out + (c0 + j) * HW + gpx0 + px0) = o4;
    }

    // fused stats: per-(channel, block) sum / sumsq
    __shared__ float sred[4][CB][2];
    int lane = tid & 63, wave = tid >> 6;
    #pragma unroll
    for (int j = 0; j < CB; ++j) {
        float s  = acc[j][0] + acc[j][1] + acc[j][2] + acc[j][3];
        float qq = acc[j][0] * acc[j][0] + acc[j][1] * acc[j][1]
                 + acc[j][2] * acc[j][2] + acc[j][3] * acc[j][3];
        #pragma unroll
        for (int off = 1; off < 64; off <<= 1) {
            s  += __shfl_xor(s, off, 64);
            qq += __shfl_xor(qq, off, 64);
        }
        if (lane == 0) { sred[wave][j][0] = s; sred[wave][j][1] = qq; }
    }
    __syncthreads();
    if (tid < CB) {
        float s  = sred[0][tid][0] + sred[1][tid][0] + sred[2][tid][0] + sred[3][tid][0];
        float qq = sred[0][tid][1] + sred[1][tid][1] + sred[2][tid][1] + sred[3][tid][1];
        int c = c0 + tid;
        part[(c * gridDim.x + blockIdx.x) * 2 + 0] = s;
        part[(c * gridDim.x + blockIdx.x) * 2 + 1] = qq;
    }
}

// ---------------- reduce per-block partials -> per-channel (mean, rsqrt(var)) ----------------
__global__ void ln_finalize_k(const float* __restrict__ part, float* __restrict__ stats,
                              int C, int nb, float invHW) {
    int c = threadIdx.x;
    if (c >= C) return;
    float s = 0.f, s2 = 0.f;
    for (int i = 0; i < nb; ++i) {
        s  += part[(c * nb + i) * 2 + 0];
        s2 += part[(c * nb + i) * 2 + 1];
    }
    float m = s * invHW;
    float var = s2 * invHW - m * m;
    if (var < 0.f) var = 0.f;
    stats[c * 2 + 0] = m;
    stats[c * 2 + 1] = rsqrtf(var + 1e-6f);
}

// ---------------- LN apply (+relu): 2 stat loads per thread (feeds next conv) ----------------
__global__ __launch_bounds__(256) void ln_apply_k(
    float* __restrict__ buf, const float* __restrict__ stats,
    const float* __restrict__ g, const float* __restrict__ b, int HW) {
    int i = blockIdx.x * 256 + threadIdx.x;
    int c = i / HW;      // HW is a power of two
    int hw = i % HW;
    float m = stats[c * 2], inv = stats[c * 2 + 1];
    float x = buf[i];
    float r = fmaf((x - m) * inv, g[hw], b[hw]);
    buf[i] = fmaxf(r, 0.f);
}

// ---------------- adaptive 3x3 avg pool of relu(LN(x)), no materialization ----------------
__global__ __launch_bounds__(256) void apool3ln_k(
    const float* __restrict__ in, const float* __restrict__ stats,
    const float* __restrict__ g, const float* __restrict__ b,
    float* __restrict__ gfc, int H, int W, int colOff) {
    int c = (int)blockIdx.x / 9;
    int bin = (int)blockIdx.x % 9;
    int bh = bin / 3, bw = bin % 3;
    int hs = bh * H / 3, he = ((bh + 1) * H + 2) / 3;
    int wsx = bw * W / 3, we = ((bw + 1) * W + 2) / 3;
    int rw = we - wsx, rh = he - hs, n = rw * rh;
    const float* bb = in + c * H * W;
    float m = stats[c * 2], inv = stats[c * 2 + 1];   // c uniform per block -> scalar
    float s = 0.f;
    for (int t = threadIdx.x; t < n; t += 256) {
        int iy = t / rw, ix = t % rw;
        int hw = (hs + iy) * W + (wsx + ix);
        float x = bb[hw];
        float r = fmaf((x - m) * inv, g[hw], b[hw]);  // bit-identical to ln_apply->apool
        s += fmaxf(r, 0.f);
    }
    __shared__ float rs[256];
    rs[threadIdx.x] = s;
    __syncthreads();
    for (int st = 128; st > 0; st >>= 1) {
        if (threadIdx.x < st) rs[threadIdx.x] += rs[threadIdx.x + st];
        __syncthreads();
    }
    if (threadIdx.x == 0) gfc[c * 18 + colOff + bin] = rs[0] / (float)n;
}

// ---------------- conv1d (42->779) + LN(18) + relu ----------------
__global__ __launch_bounds__(64) void gt1_k(const float* __restrict__ gfc,
                                            const float* __restrict__ w,
                                            const float* __restrict__ g,
                                            const float* __restrict__ b,
                                            float* __restrict__ outh) {
    int o = blockIdx.x;     // 779
    int p = threadIdx.x;
    __shared__ float vals[18];
    if (p < 18) {
        float acc = 0.f;
        const float* wo = w + o * 42 * 3;
        for (int c = 0; c < 42; ++c) {
            const float* gr = gfc + c * 18;
            #pragma unroll
            for (int k = 0; k < 3; ++k) {
                int pk = p + k - 1;
                if (pk >= 0 && pk < 18) acc = fmaf(wo[c * 3 + k], gr[pk], acc);
            }
        }
        vals[p] = acc;
    }
    __syncthreads();
    if (p < 18) {
        float s = 0.f, s2 = 0.f;
        #pragma unroll
        for (int j = 0; j < 18; ++j) { float x = vals[j]; s += x; s2 += x * x; }
        float m = s / 18.f;
        float var = s2 / 18.f - m * m;
        if (var < 0.f) var = 0.f;
        float inv = rsqrtf(var + 1e-6f);
        float r = fmaf((vals[p] - m) * inv, g[p], b[p]);
        outh[o * 18 + p] = fmaxf(r, 0.f);
    }
}

// ---------------- conv1d (779->1558) + LN(18) + relu -> vf cols 11..28 ----------------
// 4 waves per block; each wave covers a contiguous quarter of the 779 channels.
__global__ __launch_bounds__(256) void gt2_k(const float* __restrict__ h,
                                             const float* __restrict__ w,
                                             const float* __restrict__ g,
                                             const float* __restrict__ b,
                                             float* __restrict__ vf) {
    int o = blockIdx.x;     // 1558
    int t = threadIdx.x, lane = t & 63, wave = t >> 6;
    __shared__ float red[4][18];
    float part[18];
    #pragma unroll
    for (int p = 0; p < 18; ++p) part[p] = 0.f;
    int c0 = wave * 195;
    int c1 = c0 + 195; if (c1 > HALF_V) c1 = HALF_V;
    for (int c = c0 + lane; c < c1; c += 64) {
        const float* wr = w + (o * HALF_V + c) * 3;
        float w0 = wr[0], w1 = wr[1], w2 = wr[2];
        const float* hr = h + c * 18;
        float hv[18];
        #pragma unroll
        for (int p = 0; p < 18; ++p) hv[p] = hr[p];
        #pragma unroll
        for (int p = 0; p < 18; ++p) {
            float a = w1 * hv[p];
            if (p > 0)  a = fmaf(w0, hv[p - 1], a);
            if (p < 17) a = fmaf(w2, hv[p + 1], a);
            part[p] += a;
        }
    }
    #pragma unroll
    for (int p = 0; p < 18; ++p) {
        float vv = part[p];
        #pragma unroll
        for (int off = 32; off > 0; off >>= 1) vv += __shfl_xor(vv, off, 64);
        part[p] = vv;
    }
    if (lane == 0) {
        #pragma unroll
        for (int p = 0; p < 18; ++p) red[wave][p] = part[p];
    }
    __syncthreads();
    if (t < 18) {
        float s = red[0][t] + red[1][t] + red[2][t] + red[3][t];
        red[0][t] = s;
    }
    __syncthreads();
    if (t < 18) {
        float s = 0.f, s2 = 0.f;
        #pragma unroll
        for (int j = 0; j < 18; ++j) { float x = red[0][j]; s += x; s2 += x * x; }
        float m = s / 18.f;
        float var = s2 / 18.f - m * m;
        if (var < 0.f) var = 0.f;
        float inv = rsqrtf(var + 1e-6f);
        float r = fmaf((red[0][t] - m) * inv, g[t], b[t]);
        vf[o * 32 + 11 + t] = fmaxf(r, 0.f);
    }
}

// ---------------- argmin: one THREAD per query, wave-uniform vertex scan ----------------
__global__ void vprep_k(const float* __restrict__ vert, float4* __restrict__ v4) {
    int i = blockIdx.x * 64 + threadIdx.x;
    if (i >= NV_) return;
    float x = vert[i * 3 + 0], y = vert[i * 3 + 1], z = vert[i * 3 + 2];
    float pn = __fadd_rn(__fadd_rn(__fmul_rn(x, x), __fmul_rn(y, y)), __fmul_rn(z, z));
    v4[i] = make_float4(x, y, z, pn);
}

__global__ __launch_bounds__(256) void argmin_part_k(
    const float* __restrict__ v, const float4* __restrict__ v4,
    float* __restrict__ bestd, int* __restrict__ besti) {
    int q = blockIdx.x * 256 + threadIdx.x;
    int r = blockIdx.y;
    int p0 = r * VCHUNK;
    int p1 = p0 + VCHUNK; if (p1 > NV_) p1 = NV_;
    float vx = v[q * 3 + 0], vy = v[q * 3 + 1], vz = v[q * 3 + 2];
    float vn = __fadd_rn(__fadd_rn(__fmul_rn(vx, vx), __fmul_rn(vy, vy)), __fmul_rn(vz, vz));
    float best = 3.4e38f;
    int bi = p0;
    // d2 = (|v|^2 + |p|^2) - 2*(v.p); np rounding preserved (no fma contraction).
    // v4[p] is wave-uniform -> scalar K$ loads; strict < keeps smallest p on ties.
    #pragma unroll 4
    for (int p = p0; p < p1; ++p) {
        float4 pv = v4[p];
        float dot = __fadd_rn(__fadd_rn(__fmul_rn(vx, pv.x), __fmul_rn(vy, pv.y)), __fmul_rn(vz, pv.z));
        float d2 = __fsub_rn(__fadd_rn(vn, pv.w), __fmul_rn(2.f, dot));
        if (d2 < best) { best = d2; bi = p; }
    }
    bestd[r * NQ_ + q] = best;
    besti[r * NQ_ + q] = bi;
}

__global__ __launch_bounds__(256) void argmin_comb_k(
    const float* __restrict__ bestd, const int* __restrict__ besti,
    int* __restrict__ idx) {
    int q = blockIdx.x * 256 + threadIdx.x;
    float best = bestd[q];
    int bi = besti[q];
    #pragma unroll
    for (int r = 1; r < VSPLIT; ++r) {
        float d = bestd[r * NQ_ + q];
        int i2 = besti[r * NQ_ + q];
        if (d < best) { best = d; bi = i2; }   // ranges ascend in p; strict < keeps first min
    }
    idx[q] = bi;
}

// ---------------- weight f32 -> bf16 (with row zero-padding) ----------------
// wb layout (shorts): [0,9216) atw1 ; [9216,10752) atw2 pad to 16 rows ;
//                     [10752,19968) fcw1 ; [19968,24576) fcw2 pad to 48 rows
__global__ void wcvt_k(const float* __restrict__ atw1, const float* __restrict__ atw2,
                       const float* __restrict__ fcw1, const float* __restrict__ fcw2,
                       short* __restrict__ wb) {
    int i = blockIdx.x * 256 + threadIdx.x;   // grid 96 -> 24576
    short v = 0;
    if (i < 9216) v = f2b(atw1[i]);
    else if (i < 10752) { int j = i - 9216; v = (j < 576) ? f2b(atw2[j]) : (short)0; }
    else if (i < 19968) v = f2b(fcw1[i - 10752]);
    else { int j = i - 19968; v = (j < 3840) ? f2b(fcw2[j]) : (short)0; }
    wb[i] = v;
}

// ---------------- MFMA MLP: 16 queries per wave, 64 per block ----------------
#define YP 104   // padded LDS row stride in shorts (2-way bank aliasing only)

__global__ __launch_bounds__(256) void mlp_mfma_k(
    const int* __restrict__ idx,
    const float* __restrict__ vvis, const float* __restrict__ qvis,
    const float* __restrict__ ixy, const float* __restrict__ fxy,
    const float* __restrict__ lat, const float* __restrict__ vf,
    const short* __restrict__ wb, float* __restrict__ out) {
    __shared__ short Y[64 * YP];
    __shared__ short Hb[64 * YP];
    __shared__ float A6[64 * 8];
    int t = threadIdx.x;
    int lane = t & 63, wave = t >> 6;
    int q0 = blockIdx.x * 64;

    // ---- y build: 4 lanes per query, bf16 into LDS; keep f32 copy in regs ----
    int ql = t >> 2, part = t & 3;
    int q = q0 + ql;
    int bi = idx[q];
    int bi2 = bi + HALF_V; if (bi2 >= NV_) bi2 -= NV_;
    const float* f  = vf + bi * 32;
    const float* ft = vf + bi2 * 32;
    float vis = vvis[bi], vist = vvis[bi2];
    short* yr = &Y[ql * YP];
    float myv[24];
    #pragma unroll
    for (int jj = 0; jj < 24; ++jj) {
        int j = part * 24 + jj;
        float val;
        if (j < 3)       val = ixy[q * 3 + j];
        else if (j < 11) val = fxy[q * 8 + j - 3];
        else if (j < 22) val = f[j - 11] * vis;
        else if (j < 33) val = ft[j - 22] * vist;
        else if (j < 51) val = f[11 + j - 33] * vis;
        else if (j < 69) val = ft[11 + j - 51] * vist;
        else if (j < 93) val = lat[q * 24 + j - 69];
        else if (j == 93) val = qvis[q];
        else if (j == 94) val = vis;
        else              val = vist;
        myv[jj] = val;
        yr[j] = f2b(val);
    }
    __syncthreads();

    int nloc = lane & 15, quad = lane >> 4;
    const short* Ya = &Y[(wave * 16 + nloc) * YP];
    const short* Ha = &Hb[(wave * 16 + nloc) * YP];
    int hrow = wave * 16 + quad * 4;    // C-layout row base for this lane

    // ---- GEMM1: H = relu(Y x atw1^T) ----
    f32x4 acc[6];
    #pragma unroll
    for (int nt = 0; nt < 6; ++nt) acc[nt] = (f32x4){0.f, 0.f, 0.f, 0.f};
    #pragma unroll
    for (int k0 = 0; k0 < 96; k0 += 32) {
        bf16x8 a = *(const bf16x8*)(Ya + k0 + quad * 8);
        #pragma unroll
        for (int nt = 0; nt < 6; ++nt) {
            bf16x8 b = *(const bf16x8*)(wb + (nt * 16 + nloc) * 96 + k0 + quad * 8);
            acc[nt] = __builtin_amdgcn_mfma_f32_16x16x32_bf16(a, b, acc[nt], 0, 0, 0);
        }
    }
    #pragma unroll
    for (int nt = 0; nt < 6; ++nt)
        #pragma unroll
        for (int r = 0; r < 4; ++r)
            Hb[(hrow + r) * YP + nt * 16 + nloc] = f2b(fmaxf(acc[nt][r], 0.f));
    __syncthreads();

    // ---- GEMM2: at6 = sigmoid(H x atw2^T) ----
    {
        const short* w2 = wb + 9216;
        f32x4 a2 = (f32x4){0.f, 0.f, 0.f, 0.f};
        #pragma unroll
        for (int k0 = 0; k0 < 96; k0 += 32) {
            bf16x8 a = *(const bf16x8*)(Ha + k0 + quad * 8);
            bf16x8 b = *(const bf16x8*)(w2 + nloc * 96 + k0 + quad * 8);
            a2 = __builtin_amdgcn_mfma_f32_16x16x32_bf16(a, b, a2, 0, 0, 0);
        }
        if (nloc < 6) {
            #pragma unroll
            for (int r = 0; r < 4; ++r)
                A6[(hrow + r) * 8 + nloc] = 1.f / (1.f + expf(-a2[r]));
        }
    }
    __syncthreads();

    // ---- scale Y in place from f32 register copy ----
    {
        const float* ap = &A6[ql * 8];
        #pragma unroll
        for (int jj = 0; jj < 24; ++jj) {
            int j = part * 24 + jj;
            float s;
            if (j < 11)      s = ap[0];
            else if (j < 22) s = ap[1];
            else if (j < 33) s = ap[2];
            else if (j < 51) s = ap[3];
            else if (j < 69) s = ap[4];
            else if (j < 93) s = ap[5];
            else             s = 1.f;
            yr[j] = f2b(myv[jj] * s);
        }
    }
    __syncthreads();

    // ---- GEMM3: H2 = relu(Y2 x fcw1^T) ----
    {
        const short* w3 = wb + 10752;
        #pragma unroll
        for (int nt = 0; nt < 6; ++nt) acc[nt] = (f32x4){0.f, 0.f, 0.f, 0.f};
        #pragma unroll
        for (int k0 = 0; k0 < 96; k0 += 32) {
            bf16x8 a = *(const bf16x8*)(Ya + k0 + quad * 8);
            #pragma unroll
            for (int nt = 0; nt < 6; ++nt) {
                bf16x8 b = *(const bf16x8*)(w3 + (nt * 16 + nloc) * 96 + k0 + quad * 8);
                acc[nt] = __builtin_amdgcn_mfma_f32_16x16x32_bf16(a, b, acc[nt], 0, 0, 0);
            }
        }
        #pragma unroll
        for (int nt = 0; nt < 6; ++nt)
            #pragma unroll
            for (int r = 0; r < 4; ++r)
                Hb[(hrow + r) * YP + nt * 16 + nloc] = f2b(fmaxf(acc[nt][r], 0.f));
    }
    __syncthreads();

    // ---- GEMM4: OUT = H2 x fcw2^T ----
    {
        const short* w4 = wb + 19968;
        f32x4 oacc[3];
        #pragma unroll
        for (int nt = 0; nt < 3; ++nt) oacc[nt] = (f32x4){0.f, 0.f, 0.f, 0.f};
        #pragma unroll
        for (int k0 = 0; k0 < 96; k0 += 32) {
            bf16x8 a = *(const bf16x8*)(Ha + k0 + quad * 8);
            #pragma unroll
            for (int nt = 0; nt < 3; ++nt) {
                bf16x8 b = *(const bf16x8*)(w4 + (nt * 16 + nloc) * 96 + k0 + quad * 8);
                oacc[nt] = __builtin_amdgcn_mfma_f32_16x16x32_bf16(a, b, oacc[nt], 0, 0, 0);
            }
        }
        #pragma unroll
        for (int nt = 0; nt < 3; ++nt) {
            int oc = nt * 16 + nloc;
            if (oc < 40) {
                #pragma unroll
                for (int r = 0; r < 4; ++r)
                    out[(q0 + hrow + r) * 40 + oc] = oacc[nt][r];
            }
        }
    }
}

extern "C" void kernel_launch(void* const* d_in, const int* in_sizes, int n_in,
                              void* d_out, int out_size, void* d_ws, size_t ws_size,
                              hipStream_t stream) {
    const float* vert_xy = (const float*)d_in[0];
    const float* ft1     = (const float*)d_in[1];
    const float* ft_xy   = (const float*)d_in[2];
    const float* vert    = (const float*)d_in[3];
    const float* v       = (const float*)d_in[4];
    const float* vvis    = (const float*)d_in[5];
    const float* qvis    = (const float*)d_in[6];
    const float* ixy     = (const float*)d_in[7];
    const float* img     = (const float*)d_in[8];
    const float* lat     = (const float*)d_in[9];
    const float* fcw1    = (const float*)d_in[10];
    const float* fcw2    = (const float*)d_in[11];
    const float* atw1    = (const float*)d_in[12];
    const float* atw2    = (const float*)d_in[13];
    const float* gtw1    = (const float*)d_in[14];
    const float* gtg1    = (const float*)d_in[15];
    const float* gtb1    = (const float*)d_in[16];
    const float* gtw2    = (const float*)d_in[17];
    const float* gtg2    = (const float*)d_in[18];
    const float* gtb2    = (const float*)d_in[19];
    const float* c3w1    = (const float*)d_in[20];
    const float* c3g1    = (const float*)d_in[21];
    const float* c3b1    = (const float*)d_in[22];
    const float* c3w2    = (const float*)d_in[23];
    const float* c3g2    = (const float*)d_in[24];
    const float* c3b2    = (const float*)d_in[25];
    const float* c4w1    = (const float*)d_in[26];
    const float* c4g1    = (const float*)d_in[27];
    const float* c4b1    = (const float*)d_in[28];
    const float* c4w2    = (const float*)d_in[29];
    const float* c4g2    = (const float*)d_in[30];
    const float* c4b2    = (const float*)d_in[31];
    float* out = (float*)d_out;
    float* ws  = (float*)d_ws;
    float* stats = ws + WS_STATS;
    float* gfc   = ws + WS_GFC;
    float* gth   = ws + WS_GTH;
    float* vfb   = ws + WS_VF;
    float* c3a   = ws + WS_C3A;
    float* c3bb  = ws + WS_C3B;
    float* c4a   = ws + WS_C4A;
    float* c4bb  = ws + WS_C4B;
    float* part_c3 = ws + WS_C4A;            // c4a not live during c3 chain
    short* wbf     = (short*)(ws + WS_C3A);  // c3a dead after c3 conv2 (24576 shorts)
    float* part_c4 = ws + WS_C3B;            // c3bb dead after apool(c3)
    // after apool(c4), c4bb region is dead; carve argmin scratch out of it:
    int*    idx   = (int*)(ws + WS_C4B);                     // 65536 ints
    float*  bestd = ws + WS_C4B + 65536;                     // 8*65536 floats
    int*    besti = (int*)(ws + WS_C4B + 65536 + 524288);    // 8*65536 ints
    float4* vert4 = (float4*)(ws + WS_C4B + 65536 + 1048576); // 1558 float4

    feat_sample_k<<<25, 64, 0, stream>>>(vert_xy, img, ft1, vfb);

    // c3 chain: ft1 (8,64,64) -> (21) -> (42) -> pool(LN fused) -> gfc cols 9..17
    conv_lds_k<7><<<dim3(4, 3), 256, 0, stream>>>(ft1, c3w1, c3a, part_c3, 8, 64, 64);
    ln_finalize_k<<<1, 64, 0, stream>>>(part_c3, stats + 0, 21, 4, 1.f / 4096.f);
    ln_apply_k<<<21 * 16, 256, 0, stream>>>(c3a, stats + 0, c3g1, c3b1, 4096);
    conv_lds_k<7><<<dim3(4, 6), 256, 0, stream>>>(c3a, c3w2, c3bb, part_c3, 21, 64, 64);
    wcvt_k<<<96, 256, 0, stream>>>(atw1, atw2, fcw1, fcw2, wbf);  // c3a now dead
    ln_finalize_k<<<1, 64, 0, stream>>>(part_c3, stats + 128, 42, 4, 1.f / 4096.f);
    apool3ln_k<<<42 * 9, 256, 0, stream>>>(c3bb, stats + 128, c3g2, c3b2, gfc, 64, 64, 9);

    // c4 chain: img (3,256,256) -> (21) -> (42) -> pool(LN fused) -> gfc cols 0..8
    conv_lds_k<7><<<dim3(64, 3), 256, 0, stream>>>(img, c4w1, c4a, part_c4, 3, 256, 256);
    ln_finalize_k<<<1, 64, 0, stream>>>(part_c4, stats + 256, 21, 64, 1.f / 65536.f);
    ln_apply_k<<<21 * 256, 256, 0, stream>>>(c4a, stats + 256, c4g1, c4b1, 65536);
    conv_lds_k<7><<<dim3(64, 6), 256, 0, stream>>>(c4a, c4w2, c4bb, part_c4, 21, 256, 256);
    ln_finalize_k<<<1, 64, 0, stream>>>(part_c4, stats + 384, 42, 64, 1.f / 65536.f);
    apool3ln_k<<<42 * 9, 256, 0, stream>>>(c4bb, stats + 384, c4g2, c4b2, gfc, 256, 256, 0);

    // argmin AFTER apool(c4): scratch overlaps the now-dead c4bb region
    vprep_k<<<25, 64, 0, stream>>>(vert, vert4);
    argmin_part_k<<<dim3(NQ_ / 256, VSPLIT), 256, 0, stream>>>(v, vert4, bestd, besti);
    argmin_comb_k<<<NQ_ / 256, 256, 0, stream>>>(bestd, besti, idx);

    // global-token conv1d stack -> vf cols 11..28
    gt1_k<<<779, 64, 0, stream>>>(gfc, gtw1, gtg1, gtb1, gth);
    gt2_k<<<1558, 256, 0, stream>>>(gth, gtw2, gtg2, gtb2, vfb);

    // fused per-query MFMA MLP path
    mlp_mfma_k<<<NQ_ / 64, 256, 0, stream>>>(idx, vvis, qvis, ixy, ft_xy, lat, vfb,
                                             wbf, out);
}

// Round 11
// 286.506 us; speedup vs baseline: 2.2091x; 1.2516x over previous
//
#include <hip/hip_runtime.h>
#include <hip/hip_bf16.h>
#include <math.h>

#define NQ_    65536
#define NV_    1558
#define HALF_V 779
#define VSPLIT 8
#define VCHUNK 195   // ceil(1558/8); ranges ascending in p

// ws layout in floats (ws is 256 MiB; we use ~22.5 MB)
#define WS_STATS 0          //   512   (c3_1@0, c3_2@128, c4_1@256, c4_2@384)
#define WS_GFC   512
#define WS_GTH   1280
#define WS_VF    15360      // 1558*32
#define WS_C3A   65536      // 21*4096
#define WS_C3B   151552     // 42*4096
#define WS_C4A   323584     // 21*65536
#define WS_C4B   1699840    // 42*65536 (ends 4452352)
#define WS_WBF   4452352    // 24576 shorts = 12288 floats
#define WS_PART  4464640    // c3a@+0, c4a@+8192, c3b@+16384, c4b@+24576
#define WS_IDX   4500480    // 65536 ints
#define WS_BESTD 4566016    // 8*65536 floats
#define WS_BESTI 5090304    // 8*65536 ints
#define WS_VERT4 5614592    // 1558 float4 (16B aligned)

typedef __attribute__((ext_vector_type(8))) short bf16x8;
typedef __attribute__((ext_vector_type(4))) float f32x4;

__device__ __forceinline__ short f2b(float x) {
    union { __hip_bfloat16 h; short s; } u; u.h = __float2bfloat16(x); return u.s;
}

// ---------------- bilinear feature sampling body ----------------
__device__ __forceinline__ void bsample(const float* __restrict__ f, int C, int H, int W,
                                        float xn, float yn, float* __restrict__ o) {
    float x = (xn + 1.f) * 0.5f * (float)(W - 1);
    float y = (yn + 1.f) * 0.5f * (float)(H - 1);
    float x0f = floorf(x), y0f = floorf(y);
    float wx = x - x0f, wy = y - y0f;
    int x0 = (int)fminf(fmaxf(x0f, 0.f), (float)(W - 1));
    int x1 = (int)fminf(fmaxf(x0f + 1.f, 0.f), (float)(W - 1));
    int y0 = (int)fminf(fmaxf(y0f, 0.f), (float)(H - 1));
    int y1 = (int)fminf(fmaxf(y0f + 1.f, 0.f), (float)(H - 1));
    for (int c = 0; c < C; ++c) {
        const float* b = f + c * H * W;
        float v00 = b[y0 * W + x0], v01 = b[y0 * W + x1];
        float v10 = b[y1 * W + x0], v11 = b[y1 * W + x1];
        o[c] = v00 * (1.f - wx) * (1.f - wy) + v01 * wx * (1.f - wy)
             + v10 * (1.f - wx) * wy       + v11 * wx * wy;
    }
}

__device__ __forceinline__ void feat_body(int rb, int tid,
                                          const float* __restrict__ vert_xy,
                                          const float* __restrict__ img,
                                          const float* __restrict__ ft1,
                                          float* __restrict__ vf) {
    int v = rb * 256 + tid;
    if (v >= NV_) return;
    float xn = vert_xy[v * 2 + 0], yn = vert_xy[v * 2 + 1];
    float tmp[8];
    bsample(img, 3, 256, 256, xn, yn, tmp);
    float* o = vf + v * 32;
    o[0] = tmp[0]; o[1] = tmp[1]; o[2] = tmp[2];
    bsample(ft1, 8, 64, 64, xn, yn, tmp);
    #pragma unroll
    for (int c = 0; c < 8; ++c) o[3 + c] = tmp[c];
}

// ---------------- conv2d 3x3 pad1, LDS-tile staged (body) ----------------
// sm: 2 buffers of 1552 floats (8-pad | 1536 data | 8-pad). Same algorithm as
// round-10 conv_lds_k (bit-identical), parameterized for mega-kernel embedding.
template <int CB>
__device__ __forceinline__ void conv_body(
    float* __restrict__ sm, int tid,
    const float* __restrict__ in, const float* __restrict__ w,
    float* __restrict__ out, float* __restrict__ part,
    int Cin, int H, int W, int bx, int by, int nbx) {
    int c0 = by * CB;
    int gpx0 = bx * 1024;
    int y0 = gpx0 / W;
    int tileF = 1024 + 2 * W;
    int nf4 = tileF >> 2;
    int HW = H * W;
    int px0 = tid * 4;
    int ty = px0 / W, x = px0 % W;            // x multiple of 4

    float acc[CB][4];
    #pragma unroll
    for (int j = 0; j < CB; ++j)
        #pragma unroll
        for (int p = 0; p < 4; ++p) acc[j][p] = 0.f;

    const float* wbase = w + c0 * Cin * 9;
    float4 sreg[2];

    // prime stage for ci = 0
    #pragma unroll
    for (int k = 0; k < 2; ++k) {
        int idx = tid + k * 256;
        float4 v = make_float4(0.f, 0.f, 0.f, 0.f);
        if (idx < nf4) {
            int gw = idx * 4;
            int gy = y0 - 1 + gw / W, gx = gw % W;
            if (gy >= 0 && gy < H) v = *(const float4*)(in + gy * W + gx);
        }
        sreg[k] = v;
    }
    #pragma unroll
    for (int k = 0; k < 2; ++k) {
        int idx = tid + k * 256;
        if (idx < nf4) *(float4*)(sm + 8 + idx * 4) = sreg[k];
    }
    __syncthreads();

    for (int ci = 0; ci < Cin; ++ci) {
        if (ci + 1 < Cin) {
            const float* ipn = in + (ci + 1) * HW;
            #pragma unroll
            for (int k = 0; k < 2; ++k) {
                int idx = tid + k * 256;
                float4 v = make_float4(0.f, 0.f, 0.f, 0.f);
                if (idx < nf4) {
                    int gw = idx * 4;
                    int gy = y0 - 1 + gw / W, gx = gw % W;
                    if (gy >= 0 && gy < H) v = *(const float4*)(ipn + gy * W + gx);
                }
                sreg[k] = v;
            }
        }
        {
            const float* tl = sm + (ci & 1) * 1552 + 8;
            float win[3][6];
            #pragma unroll
            for (int r = 0; r < 3; ++r) {
                const float* lrow = tl + (ty + r) * W + x;
                float4 B = *(const float4*)(lrow);
                float4 A = *(const float4*)(lrow - 4);   // pad covers x==0
                float4 C = *(const float4*)(lrow + 4);   // pad covers tile end
                win[r][0] = (x > 0) ? A.w : 0.f;
                win[r][1] = B.x; win[r][2] = B.y; win[r][3] = B.z; win[r][4] = B.w;
                win[r][5] = (x + 4 < W) ? C.x : 0.f;
            }
            const float* wc = wbase + ci * 9;
            #pragma unroll
            for (int j = 0; j < CB; ++j) {
                const float* wj = wc + j * Cin * 9;   // wave-uniform -> scalar loads
                #pragma unroll
                for (int r = 0; r < 3; ++r) {
                    float w0 = wj[r * 3 + 0], w1 = wj[r * 3 + 1], w2 = wj[r * 3 + 2];
                    #pragma unroll
                    for (int p = 0; p < 4; ++p)
                        acc[j][p] = fmaf(w0, win[r][p],
                                    fmaf(w1, win[r][p + 1],
                                    fmaf(w2, win[r][p + 2], acc[j][p])));
                }
            }
        }
        if (ci + 1 < Cin) {
            float* tn = sm + ((ci + 1) & 1) * 1552 + 8;
            #pragma unroll
            for (int k = 0; k < 2; ++k) {
                int idx = tid + k * 256;
                if (idx < nf4) *(float4*)(tn + idx * 4) = sreg[k];
            }
        }
        __syncthreads();
    }

    #pragma unroll
    for (int j = 0; j < CB; ++j) {
        float4 o4 = make_float4(acc[j][0], acc[j][1], acc[j][2], acc[j][3]);
        *(float4*)(out + (c0 + j) * HW + gpx0 + px0) = o4;
    }

    // fused stats: per-(channel, block) sum / sumsq. Reuse sm as sred
    // (all tile reads completed before the loop's final barrier).
    float* sred = sm;   // [wave][CB][2]
    int lane = tid & 63, wave = tid >> 6;
    #pragma unroll
    for (int j = 0; j < CB; ++j) {
        float s  = acc[j][0] + acc[j][1] + acc[j][2] + acc[j][3];
        float qq = acc[j][0] * acc[j][0] + acc[j][1] * acc[j][1]
                 + acc[j][2] * acc[j][2] + acc[j][3] * acc[j][3];
        #pragma unroll
        for (int off = 1; off < 64; off <<= 1) {
            s  += __shfl_xor(s, off, 64);
            qq += __shfl_xor(qq, off, 64);
        }
        if (lane == 0) { sred[(wave * CB + j) * 2 + 0] = s; sred[(wave * CB + j) * 2 + 1] = qq; }
    }
    __syncthreads();
    if (tid < CB) {
        float s = 0.f, qq = 0.f;
        #pragma unroll
        for (int wv = 0; wv < 4; ++wv) {
            s  += sred[(wv * CB + tid) * 2 + 0];
            qq += sred[(wv * CB + tid) * 2 + 1];
        }
        int c = c0 + tid;
        part[(c * nbx + bx) * 2 + 0] = s;
        part[(c * nbx + bx) * 2 + 1] = qq;
    }
}

// ---------------- weight cvt body ----------------
__device__ __forceinline__ void wcvt_body(int rb, int tid,
    const float* __restrict__ atw1, const float* __restrict__ atw2,
    const float* __restrict__ fcw1, const float* __restrict__ fcw2,
    short* __restrict__ wb) {
    int i = rb * 256 + tid;
    short v = 0;
    if (i < 9216) v = f2b(atw1[i]);
    else if (i < 10752) { int j = i - 9216; v = (j < 576) ? f2b(atw2[j]) : (short)0; }
    else if (i < 19968) v = f2b(fcw1[i - 10752]);
    else { int j = i - 19968; v = (j < 3840) ? f2b(fcw2[j]) : (short)0; }
    wb[i] = v;
}

// ---------------- vprep body ----------------
__device__ __forceinline__ void vprep_body(int rb, int tid,
    const float* __restrict__ vert, float4* __restrict__ v4) {
    int i = rb * 256 + tid;
    if (i >= NV_) return;
    float x = vert[i * 3 + 0], y = vert[i * 3 + 1], z = vert[i * 3 + 2];
    float pn = __fadd_rn(__fadd_rn(__fmul_rn(x, x), __fmul_rn(y, y)), __fmul_rn(z, z));
    v4[i] = make_float4(x, y, z, pn);
}

// ---------------- argmin body ----------------
__device__ __forceinline__ void argmin_body(int qb, int r, int tid,
    const float* __restrict__ v, const float4* __restrict__ v4,
    float* __restrict__ bestd, int* __restrict__ besti) {
    int q = qb * 256 + tid;
    int p0 = r * VCHUNK;
    int p1 = p0 + VCHUNK; if (p1 > NV_) p1 = NV_;
    float vx = v[q * 3 + 0], vy = v[q * 3 + 1], vz = v[q * 3 + 2];
    float vn = __fadd_rn(__fadd_rn(__fmul_rn(vx, vx), __fmul_rn(vy, vy)), __fmul_rn(vz, vz));
    float best = 3.4e38f;
    int bi = p0;
    // d2 = (|v|^2 + |p|^2) - 2*(v.p); np rounding preserved (no fma contraction).
    #pragma unroll 4
    for (int p = p0; p < p1; ++p) {
        float4 pv = v4[p];
        float dot = __fadd_rn(__fadd_rn(__fmul_rn(vx, pv.x), __fmul_rn(vy, pv.y)), __fmul_rn(vz, pv.z));
        float d2 = __fsub_rn(__fadd_rn(vn, pv.w), __fmul_rn(2.f, dot));
        if (d2 < best) { best = d2; bi = p; }
    }
    bestd[r * NQ_ + q] = best;
    besti[r * NQ_ + q] = bi;
}

// ================ mega-kernel A: c4conv1 + c3conv1 + feat_sample + wcvt + vprep ================
__global__ __launch_bounds__(256) void megaA_k(
    const float* __restrict__ img, const float* __restrict__ c4w1,
    float* __restrict__ c4a, float* __restrict__ part_c4a,
    const float* __restrict__ ft1, const float* __restrict__ c3w1,
    float* __restrict__ c3a, float* __restrict__ part_c3a,
    const float* __restrict__ vert_xy, float* __restrict__ vfb,
    const float* __restrict__ atw1, const float* __restrict__ atw2,
    const float* __restrict__ fcw1, const float* __restrict__ fcw2,
    short* __restrict__ wbf,
    const float* __restrict__ vert, float4* __restrict__ vert4) {
    __shared__ float sm[2 * 1552];
    int rb = blockIdx.x, tid = threadIdx.x;
    if (rb < 192)       conv_body<7>(sm, tid, img, c4w1, c4a, part_c4a, 3, 256, 256, rb % 64, rb / 64, 64);
    else if (rb < 204)  { int r = rb - 192; conv_body<7>(sm, tid, ft1, c3w1, c3a, part_c3a, 8, 64, 64, r % 4, r / 4, 4); }
    else if (rb < 211)  feat_body(rb - 204, tid, vert_xy, img, ft1, vfb);
    else if (rb < 307)  wcvt_body(rb - 211, tid, atw1, atw2, fcw1, fcw2, wbf);
    else                vprep_body(rb - 307, tid, vert, vert4);
}

// ================ mega-kernel B: c4conv2 + c3conv2 + argmin_part ================
__global__ __launch_bounds__(256) void megaB_k(
    const float* __restrict__ c4a, const float* __restrict__ c4w2,
    float* __restrict__ c4bb, float* __restrict__ part_c4b,
    const float* __restrict__ c3a, const float* __restrict__ c3w2,
    float* __restrict__ c3bb, float* __restrict__ part_c3b,
    const float* __restrict__ v, const float4* __restrict__ vert4,
    float* __restrict__ bestd, int* __restrict__ besti) {
    __shared__ float sm[2 * 1552];
    int rb = blockIdx.x, tid = threadIdx.x;
    if (rb < 384)       conv_body<7>(sm, tid, c4a, c4w2, c4bb, part_c4b, 21, 256, 256, rb % 64, rb / 64, 64);
    else if (rb < 408)  { int r = rb - 384; conv_body<7>(sm, tid, c3a, c3w2, c3bb, part_c3b, 21, 64, 64, r % 4, r / 4, 4); }
    else                { int r = rb - 408; argmin_body(r % 256, r / 256, tid, v, vert4, bestd, besti); }
}

// ---------------- ln finalize x2 (one block each) ----------------
__device__ __forceinline__ void lnfin_body(int c, const float* __restrict__ part,
                                           float* __restrict__ stats, int C, int nb, float invHW) {
    if (c >= C) return;
    float s = 0.f, s2 = 0.f;
    for (int i = 0; i < nb; ++i) {
        s  += part[(c * nb + i) * 2 + 0];
        s2 += part[(c * nb + i) * 2 + 1];
    }
    float m = s * invHW;
    float var = s2 * invHW - m * m;
    if (var < 0.f) var = 0.f;
    stats[c * 2 + 0] = m;
    stats[c * 2 + 1] = rsqrtf(var + 1e-6f);
}

__global__ void lnfin2_k(const float* __restrict__ pa, float* __restrict__ sa, int Ca, int nba, float inva,
                         const float* __restrict__ pb, float* __restrict__ sb, int Cb, int nbb, float invb) {
    if (blockIdx.x == 0) lnfin_body(threadIdx.x, pa, sa, Ca, nba, inva);
    else                 lnfin_body(threadIdx.x, pb, sb, Cb, nbb, invb);
}

// ---------------- LN apply (+relu) for both chains in one dispatch ----------------
__global__ __launch_bounds__(256) void lnapply2_k(
    float* __restrict__ c4a, const float* __restrict__ st4,
    const float* __restrict__ g4, const float* __restrict__ b4,
    float* __restrict__ c3a, const float* __restrict__ st3,
    const float* __restrict__ g3, const float* __restrict__ b3) {
    int rb = blockIdx.x, tid = threadIdx.x;
    if (rb < 5376) {
        int i = rb * 256 + tid;
        int c = i >> 16, hw = i & 65535;
        float m = st4[c * 2], inv = st4[c * 2 + 1];
        float x = c4a[i];
        c4a[i] = fmaxf(fmaf((x - m) * inv, g4[hw], b4[hw]), 0.f);
    } else {
        int i = (rb - 5376) * 256 + tid;
        int c = i >> 12, hw = i & 4095;
        float m = st3[c * 2], inv = st3[c * 2 + 1];
        float x = c3a[i];
        c3a[i] = fmaxf(fmaf((x - m) * inv, g3[hw], b3[hw]), 0.f);
    }
}

// ---------------- apool3(relu(LN(x))) both chains + argmin combine ----------------
__device__ __forceinline__ void apool_body(int rb, int tid, float* __restrict__ rs,
    const float* __restrict__ in, const float* __restrict__ stats,
    const float* __restrict__ g, const float* __restrict__ b,
    float* __restrict__ gfc, int H, int W, int colOff) {
    int c = rb / 9, bin = rb % 9;
    int bh = bin / 3, bw = bin % 3;
    int hs = bh * H / 3, he = ((bh + 1) * H + 2) / 3;
    int wsx = bw * W / 3, we = ((bw + 1) * W + 2) / 3;
    int rw = we - wsx, rh = he - hs, n = rw * rh;
    const float* bb = in + c * H * W;
    float m = stats[c * 2], inv = stats[c * 2 + 1];
    float s = 0.f;
    for (int t = tid; t < n; t += 256) {
        int iy = t / rw, ix = t % rw;
        int hw = (hs + iy) * W + (wsx + ix);
        float x = bb[hw];
        float r = fmaf((x - m) * inv, g[hw], b[hw]);  // bit-identical to ln_apply->apool
        s += fmaxf(r, 0.f);
    }
    rs[tid] = s;
    __syncthreads();
    for (int st = 128; st > 0; st >>= 1) {
        if (tid < st) rs[tid] += rs[tid + st];
        __syncthreads();
    }
    if (tid == 0) gfc[c * 18 + colOff + bin] = rs[0] / (float)n;
}

__global__ __launch_bounds__(256) void apoolcomb_k(
    const float* __restrict__ c4bb, const float* __restrict__ st4,
    const float* __restrict__ g4, const float* __restrict__ b4,
    const float* __restrict__ c3bb, const float* __restrict__ st3,
    const float* __restrict__ g3, const float* __restrict__ b3,
    float* __restrict__ gfc,
    const float* __restrict__ bestd, const int* __restrict__ besti,
    int* __restrict__ idx) {
    __shared__ float rs[256];
    int rb = blockIdx.x, tid = threadIdx.x;
    if (rb < 378)       apool_body(rb, tid, rs, c4bb, st4, g4, b4, gfc, 256, 256, 0);
    else if (rb < 756)  apool_body(rb - 378, tid, rs, c3bb, st3, g3, b3, gfc, 64, 64, 9);
    else {
        int q = (rb - 756) * 256 + tid;
        float best = bestd[q];
        int bi = besti[q];
        #pragma unroll
        for (int r = 1; r < VSPLIT; ++r) {
            float d = bestd[r * NQ_ + q];
            int i2 = besti[r * NQ_ + q];
            if (d < best) { best = d; bi = i2; }   // ranges ascend in p; strict < keeps first min
        }
        idx[q] = bi;
    }
}

// ---------------- conv1d (42->779) + LN(18) + relu ----------------
__global__ __launch_bounds__(64) void gt1_k(const float* __restrict__ gfc,
                                            const float* __restrict__ w,
                                            const float* __restrict__ g,
                                            const float* __restrict__ b,
                                            float* __restrict__ outh) {
    int o = blockIdx.x;     // 779
    int p = threadIdx.x;
    __shared__ float vals[18];
    if (p < 18) {
        float acc = 0.f;
        const float* wo = w + o * 42 * 3;
        for (int c = 0; c < 42; ++c) {
            const float* gr = gfc + c * 18;
            #pragma unroll
            for (int k = 0; k < 3; ++k) {
                int pk = p + k - 1;
                if (pk >= 0 && pk < 18) acc = fmaf(wo[c * 3 + k], gr[pk], acc);
            }
        }
        vals[p] = acc;
    }
    __syncthreads();
    if (p < 18) {
        float s = 0.f, s2 = 0.f;
        #pragma unroll
        for (int j = 0; j < 18; ++j) { float x = vals[j]; s += x; s2 += x * x; }
        float m = s / 18.f;
        float var = s2 / 18.f - m * m;
        if (var < 0.f) var = 0.f;
        float inv = rsqrtf(var + 1e-6f);
        float r = fmaf((vals[p] - m) * inv, g[p], b[p]);
        outh[o * 18 + p] = fmaxf(r, 0.f);
    }
}

// ---------------- conv1d (779->1558) + LN(18) + relu -> vf cols 11..28 ----------------
__global__ __launch_bounds__(256) void gt2_k(const float* __restrict__ h,
                                             const float* __restrict__ w,
                                             const float* __restrict__ g,
                                             const float* __restrict__ b,
                                             float* __restrict__ vf) {
    int o = blockIdx.x;     // 1558
    int t = threadIdx.x, lane = t & 63, wave = t >> 6;
    __shared__ float red[4][18];
    float part[18];
    #pragma unroll
    for (int p = 0; p < 18; ++p) part[p] = 0.f;
    int c0 = wave * 195;
    int c1 = c0 + 195; if (c1 > HALF_V) c1 = HALF_V;
    for (int c = c0 + lane; c < c1; c += 64) {
        const float* wr = w + (o * HALF_V + c) * 3;
        float w0 = wr[0], w1 = wr[1], w2 = wr[2];
        const float* hr = h + c * 18;
        float hv[18];
        #pragma unroll
        for (int p = 0; p < 18; ++p) hv[p] = hr[p];
        #pragma unroll
        for (int p = 0; p < 18; ++p) {
            float a = w1 * hv[p];
            if (p > 0)  a = fmaf(w0, hv[p - 1], a);
            if (p < 17) a = fmaf(w2, hv[p + 1], a);
            part[p] += a;
        }
    }
    #pragma unroll
    for (int p = 0; p < 18; ++p) {
        float vv = part[p];
        #pragma unroll
        for (int off = 32; off > 0; off >>= 1) vv += __shfl_xor(vv, off, 64);
        part[p] = vv;
    }
    if (lane == 0) {
        #pragma unroll
        for (int p = 0; p < 18; ++p) red[wave][p] = part[p];
    }
    __syncthreads();
    if (t < 18) {
        float s = red[0][t] + red[1][t] + red[2][t] + red[3][t];
        red[0][t] = s;
    }
    __syncthreads();
    if (t < 18) {
        float s = 0.f, s2 = 0.f;
        #pragma unroll
        for (int j = 0; j < 18; ++j) { float x = red[0][j]; s += x; s2 += x * x; }
        float m = s / 18.f;
        float var = s2 / 18.f - m * m;
        if (var < 0.f) var = 0.f;
        float inv = rsqrtf(var + 1e-6f);
        float r = fmaf((red[0][t] - m) * inv, g[t], b[t]);
        vf[o * 32 + 11 + t] = fmaxf(r, 0.f);
    }
}

// ---------------- MFMA MLP: 16 queries per wave, 64 per block ----------------
#define YP 104   // padded LDS row stride in shorts (2-way bank aliasing only)

__global__ __launch_bounds__(256) void mlp_mfma_k(
    const int* __restrict__ idx,
    const float* __restrict__ vvis, const float* __restrict__ qvis,
    const float* __restrict__ ixy, const float* __restrict__ fxy,
    const float* __restrict__ lat, const float* __restrict__ vf,
    const short* __restrict__ wb, float* __restrict__ out) {
    __shared__ short Y[64 * YP];
    __shared__ short Hb[64 * YP];
    __shared__ float A6[64 * 8];
    int t = threadIdx.x;
    int lane = t & 63, wave = t >> 6;
    int q0 = blockIdx.x * 64;

    int ql = t >> 2, part = t & 3;
    int q = q0 + ql;
    int bi = idx[q];
    int bi2 = bi + HALF_V; if (bi2 >= NV_) bi2 -= NV_;
    const float* f  = vf + bi * 32;
    const float* ft = vf + bi2 * 32;
    float vis = vvis[bi], vist = vvis[bi2];
    short* yr = &Y[ql * YP];
    float myv[24];
    #pragma unroll
    for (int jj = 0; jj < 24; ++jj) {
        int j = part * 24 + jj;
        float val;
        if (j < 3)       val = ixy[q * 3 + j];
        else if (j < 11) val = fxy[q * 8 + j - 3];
        else if (j < 22) val = f[j - 11] * vis;
        else if (j < 33) val = ft[j - 22] * vist;
        else if (j < 51) val = f[11 + j - 33] * vis;
        else if (j < 69) val = ft[11 + j - 51] * vist;
        else if (j < 93) val = lat[q * 24 + j - 69];
        else if (j == 93) val = qvis[q];
        else if (j == 94) val = vis;
        else              val = vist;
        myv[jj] = val;
        yr[j] = f2b(val);
    }
    __syncthreads();

    int nloc = lane & 15, quad = lane >> 4;
    const short* Ya = &Y[(wave * 16 + nloc) * YP];
    const short* Ha = &Hb[(wave * 16 + nloc) * YP];
    int hrow = wave * 16 + quad * 4;

    // ---- GEMM1: H = relu(Y x atw1^T) ----
    f32x4 acc[6];
    #pragma unroll
    for (int nt = 0; nt < 6; ++nt) acc[nt] = (f32x4){0.f, 0.f, 0.f, 0.f};
    #pragma unroll
    for (int k0 = 0; k0 < 96; k0 += 32) {
        bf16x8 a = *(const bf16x8*)(Ya + k0 + quad * 8);
        #pragma unroll
        for (int nt = 0; nt < 6; ++nt) {
            bf16x8 b = *(const bf16x8*)(wb + (nt * 16 + nloc) * 96 + k0 + quad * 8);
            acc[nt] = __builtin_amdgcn_mfma_f32_16x16x32_bf16(a, b, acc[nt], 0, 0, 0);
        }
    }
    #pragma unroll
    for (int nt = 0; nt < 6; ++nt)
        #pragma unroll
        for (int r = 0; r < 4; ++r)
            Hb[(hrow + r) * YP + nt * 16 + nloc] = f2b(fmaxf(acc[nt][r], 0.f));
    __syncthreads();

    // ---- GEMM2: at6 = sigmoid(H x atw2^T) ----
    {
        const short* w2 = wb + 9216;
        f32x4 a2 = (f32x4){0.f, 0.f, 0.f, 0.f};
        #pragma unroll
        for (int k0 = 0; k0 < 96; k0 += 32) {
            bf16x8 a = *(const bf16x8*)(Ha + k0 + quad * 8);
            bf16x8 b = *(const bf16x8*)(w2 + nloc * 96 + k0 + quad * 8);
            a2 = __builtin_amdgcn_mfma_f32_16x16x32_bf16(a, b, a2, 0, 0, 0);
        }
        if (nloc < 6) {
            #pragma unroll
            for (int r = 0; r < 4; ++r)
                A6[(hrow + r) * 8 + nloc] = 1.f / (1.f + expf(-a2[r]));
        }
    }
    __syncthreads();

    // ---- scale Y in place from f32 register copy ----
    {
        const float* ap = &A6[ql * 8];
        #pragma unroll
        for (int jj = 0; jj < 24; ++jj) {
            int j = part * 24 + jj;
            float s;
            if (j < 11)      s = ap[0];
            else if (j < 22) s = ap[1];
            else if (j < 33) s = ap[2];
            else if (j < 51) s = ap[3];
            else if (j < 69) s = ap[4];
            else if (j < 93) s = ap[5];
            else             s = 1.f;
            yr[j] = f2b(myv[jj] * s);
        }
    }
    __syncthreads();

    // ---- GEMM3: H2 = relu(Y2 x fcw1^T) ----
    {
        const short* w3 = wb + 10752;
        #pragma unroll
        for (int nt = 0; nt < 6; ++nt) acc[nt] = (f32x4){0.f, 0.f, 0.f, 0.f};
        #pragma unroll
        for (int k0 = 0; k0 < 96; k0 += 32) {
            bf16x8 a = *(const bf16x8*)(Ya + k0 + quad * 8);
            #pragma unroll
            for (int nt = 0; nt < 6; ++nt) {
                bf16x8 b = *(const bf16x8*)(w3 + (nt * 16 + nloc) * 96 + k0 + quad * 8);
                acc[nt] = __builtin_amdgcn_mfma_f32_16x16x32_bf16(a, b, acc[nt], 0, 0, 0);
            }
        }
        #pragma unroll
        for (int nt = 0; nt < 6; ++nt)
            #pragma unroll
            for (int r = 0; r < 4; ++r)
                Hb[(hrow + r) * YP + nt * 16 + nloc] = f2b(fmaxf(acc[nt][r], 0.f));
    }
    __syncthreads();

    // ---- GEMM4: OUT = H2 x fcw2^T ----
    {
        const short* w4 = wb + 19968;
        f32x4 oacc[3];
        #pragma unroll
        for (int nt = 0; nt < 3; ++nt) oacc[nt] = (f32x4){0.f, 0.f, 0.f, 0.f};
        #pragma unroll
        for (int k0 = 0; k0 < 96; k0 += 32) {
            bf16x8 a = *(const bf16x8*)(Ha + k0 + quad * 8);
            #pragma unroll
            for (int nt = 0; nt < 3; ++nt) {
                bf16x8 b = *(const bf16x8*)(w4 + (nt * 16 + nloc) * 96 + k0 + quad * 8);
                oacc[nt] = __builtin_amdgcn_mfma_f32_16x16x32_bf16(a, b, oacc[nt], 0, 0, 0);
            }
        }
        #pragma unroll
        for (int nt = 0; nt < 3; ++nt) {
            int oc = nt * 16 + nloc;
            if (oc < 40) {
                #pragma unroll
                for (int r = 0; r < 4; ++r)
                    out[(q0 + hrow + r) * 40 + oc] = oacc[nt][r];
            }
        }
    }
}

extern "C" void kernel_launch(void* const* d_in, const int* in_sizes, int n_in,
                              void* d_out, int out_size, void* d_ws, size_t ws_size,
                              hipStream_t stream) {
    const float* vert_xy = (const float*)d_in[0];
    const float* ft1     = (const float*)d_in[1];
    const float* ft_xy   = (const float*)d_in[2];
    const float* vert    = (const float*)d_in[3];
    const float* v       = (const float*)d_in[4];
    const float* vvis    = (const float*)d_in[5];
    const float* qvis    = (const float*)d_in[6];
    const float* ixy     = (const float*)d_in[7];
    const float* img     = (const float*)d_in[8];
    const float* lat     = (const float*)d_in[9];
    const float* fcw1    = (const float*)d_in[10];
    const float* fcw2    = (const float*)d_in[11];
    const float* atw1    = (const float*)d_in[12];
    const float* atw2    = (const float*)d_in[13];
    const float* gtw1    = (const float*)d_in[14];
    const float* gtg1    = (const float*)d_in[15];
    const float* gtb1    = (const float*)d_in[16];
    const float* gtw2    = (const float*)d_in[17];
    const float* gtg2    = (const float*)d_in[18];
    const float* gtb2    = (const float*)d_in[19];
    const float* c3w1    = (const float*)d_in[20];
    const float* c3g1    = (const float*)d_in[21];
    const float* c3b1    = (const float*)d_in[22];
    const float* c3w2    = (const float*)d_in[23];
    const float* c3g2    = (const float*)d_in[24];
    const float* c3b2    = (const float*)d_in[25];
    const float* c4w1    = (const float*)d_in[26];
    const float* c4g1    = (const float*)d_in[27];
    const float* c4b1    = (const float*)d_in[28];
    const float* c4w2    = (const float*)d_in[29];
    const float* c4g2    = (const float*)d_in[30];
    const float* c4b2    = (const float*)d_in[31];
    float* out = (float*)d_out;
    float* ws  = (float*)d_ws;
    float* stats = ws + WS_STATS;
    float* gfc   = ws + WS_GFC;
    float* gth   = ws + WS_GTH;
    float* vfb   = ws + WS_VF;
    float* c3a   = ws + WS_C3A;
    float* c3bb  = ws + WS_C3B;
    float* c4a   = ws + WS_C4A;
    float* c4bb  = ws + WS_C4B;
    short* wbf   = (short*)(ws + WS_WBF);
    float* part_c3a = ws + WS_PART + 0;
    float* part_c4a = ws + WS_PART + 8192;
    float* part_c3b = ws + WS_PART + 16384;
    float* part_c4b = ws + WS_PART + 24576;
    int*    idx   = (int*)(ws + WS_IDX);
    float*  bestd = ws + WS_BESTD;
    int*    besti = (int*)(ws + WS_BESTI);
    float4* vert4 = (float4*)(ws + WS_VERT4);

    // 1: all input-independent work in one dispatch
    megaA_k<<<314, 256, 0, stream>>>(img, c4w1, c4a, part_c4a,
                                     ft1, c3w1, c3a, part_c3a,
                                     vert_xy, vfb,
                                     atw1, atw2, fcw1, fcw2, wbf,
                                     vert, vert4);
    // 2: LN stats for both conv1 outputs
    lnfin2_k<<<2, 64, 0, stream>>>(part_c3a, stats + 0, 21, 4, 1.f / 4096.f,
                                   part_c4a, stats + 256, 21, 64, 1.f / 65536.f);
    // 3: LN apply both chains
    lnapply2_k<<<5712, 256, 0, stream>>>(c4a, stats + 256, c4g1, c4b1,
                                         c3a, stats + 0, c3g1, c3b1);
    // 4: conv2 both chains + argmin partials (independent, backfills CUs)
    megaB_k<<<2456, 256, 0, stream>>>(c4a, c4w2, c4bb, part_c4b,
                                      c3a, c3w2, c3bb, part_c3b,
                                      v, vert4, bestd, besti);
    // 5: LN stats for both conv2 outputs
    lnfin2_k<<<2, 64, 0, stream>>>(part_c3b, stats + 128, 42, 4, 1.f / 4096.f,
                                   part_c4b, stats + 384, 42, 64, 1.f / 65536.f);
    // 6: pool(relu(LN)) both chains + argmin combine
    apoolcomb_k<<<1012, 256, 0, stream>>>(c4bb, stats + 384, c4g2, c4b2,
                                          c3bb, stats + 128, c3g2, c3b2,
                                          gfc, bestd, besti, idx);
    // 7-8: global-token conv1d stack -> vf cols 11..28
    gt1_k<<<779, 64, 0, stream>>>(gfc, gtw1, gtg1, gtb1, gth);
    gt2_k<<<1558, 256, 0, stream>>>(gth, gtw2, gtg2, gtb2, vfb);
    // 9: fused per-query MFMA MLP path
    mlp_mfma_k<<<NQ_ / 64, 256, 0, stream>>>(idx, vvis, qvis, ixy, ft_xy, lat, vfb,
                                             wbf, out);
}